// Round 6
// baseline (310.292 us; speedup 1.0000x reference)
//
#include <hip/hip_runtime.h>
#include <hip/hip_bf16.h>

// Problem constants (B,N,H,W,C) = (2,512,16,32,64)
#define B_ 2
#define N_ 512
#define M_ 512
#define C_ 64
#define O1 128
#define O2 64
#define O3 32
#define PBIG 524288.0f   // B*N*M samples for BN1/BN2
#define P3   1024.0f     // B*N samples for BN3

typedef short s8v __attribute__((ext_vector_type(8)));   // 8 bf16 (4 VGPRs)
typedef float f4v __attribute__((ext_vector_type(4)));   // MFMA accumulator

// ---- workspace layout (float-element offsets) ----
#define WS_SRCN 0        //  [B][N][64]  (dead after k2 -> reused as WS_P0)
#define WS_DSTN 65536    //  [B][M][64]  (dead after k2 -> reused as WS_P0)
#define WS_P0   0        //  [B*N][128] BN1-folded per-(b,n) part (k3b)
#define WS_U    131072   //  [B][N][128] (dead after k3b -> reused as WS_Z)
#define WS_Z    131072   //  [B][N][32]  (k5 -> k6)
#define WS_V    262144   //  [B][M][128] (scaled by A1 in k3b, in place)
#define WS_DXY  393216   //  [B][M][2]
#define WS_COS  395264   //  [B][N][M]  -> ends 919552
#define WS_RMAX 919552   //  [B*N] INVERSE row max: 1/(max+1e-6)
#define WS_ST1  920576   //  [64][256] BN1 partials -> 936960
#define WS_ST2  936960   //  [64][128] BN2 partials -> 945152
#define WS_ST3  945152   //  [64][64]  BN3 partials -> 949248
#define WS_CMAX 949248   //  [B*M] INVERSE col max: 1/(max+1e-10)
#define WS_W2F  950272   //  bf16 [8192] fragment-packed W2 (k3b -> k4)
#define WS_W9S  954368   //  [3][128] A1-scaled W1 rank-1 columns
#define WS_X2   961536   //  bf16 fragment-major [B*N][4096] uint4 (64 KB per bn)

__device__ __forceinline__ unsigned short f2bf(float f){
  unsigned u = __float_as_uint(f);
  unsigned r = (u + 0x7fffu + ((u >> 16) & 1u)) >> 16;   // RNE
  return (unsigned short)r;
}
__device__ __forceinline__ float bf2f(unsigned short h){
  return __uint_as_float(((unsigned)h) << 16);
}
__device__ __forceinline__ unsigned pk2(float lo, float hi){
  return (unsigned)f2bf(lo) | ((unsigned)f2bf(hi) << 16);
}
// pack two f32 -> bf16x2 by truncation: one v_perm_b32 (used for MFMA inputs)
__device__ __forceinline__ unsigned pk_trunc(float lo, float hi){
  return __builtin_amdgcn_perm(__float_as_uint(hi), __float_as_uint(lo), 0x07060302u);
}
__device__ __forceinline__ f4v relu4(f4v z){
  z[0] = fmaxf(z[0], 0.f); z[1] = fmaxf(z[1], 0.f);
  z[2] = fmaxf(z[2], 0.f); z[3] = fmaxf(z[3], 0.f);
  return z;
}

// ---------------- K1: fused per-n (blk<1024) and per-m precompute ----------------
__global__ __launch_bounds__(128) void k1(const float* __restrict__ wxyz,
    const float* __restrict__ wpts, const float* __restrict__ lz,
    const float* __restrict__ rf3, const float* __restrict__ rf3i,
    const float* __restrict__ W1, float* __restrict__ ws){
  int t = threadIdx.x;
  if (blockIdx.x < 1024){
    int blk = blockIdx.x; int b = blk >> 9, n = blk & 511;
    int bn = b*N_ + n;
    __shared__ float wp[64]; __shared__ float sxyz[3]; __shared__ float slz; __shared__ float srn;
    if (t < 64) wp[t] = wpts[bn*64 + t];
    if (t >= 64 && t < 67) sxyz[t-64] = wxyz[bn*3 + (t-64)];
    if (t == 67) slz = lz[bn];
    __syncthreads();
    if (t < 64){
      float v = wp[t]*wp[t];
      v += __shfl_down(v,32); v += __shfl_down(v,16); v += __shfl_down(v,8);
      v += __shfl_down(v,4);  v += __shfl_down(v,2);  v += __shfl_down(v,1);
      if (t == 0) srn = 1.0f / fmaxf(sqrtf(v), 1e-12f);
    }
    __syncthreads();
    if (t < 64) ws[WS_SRCN + bn*64 + t] = wp[t]*srn;
    int o = t;
    float x = sxyz[0], y = sxyz[1], z = sxyz[2], l = slz;
    float acc = x*l*W1[0*O1+o] + y*l*W1[1*O1+o] + z*l*W1[2*O1+o]
              + wp[0]*W1[3*O1+o] + wp[1]*W1[4*O1+o]
              + x*W1[7*O1+o] + y*W1[8*O1+o];
    #pragma unroll 8
    for (int c = 0; c < 64; ++c) acc += wp[c]*W1[(10+c)*O1+o];
    ws[WS_U + bn*O1 + o] = acc;
  } else {
    int blk = blockIdx.x - 1024; int b = blk >> 9, m = blk & 511;
    int bm = b*M_ + m;
    __shared__ float rf[64]; __shared__ float sdx, sdy, srn2;
    if (t < 64) rf[t] = rf3[(b*64 + t)*512 + m];
    if (t == 64) sdx = rf3i[(b*3 + 0)*512 + m];
    if (t == 65) sdy = rf3i[(b*3 + 1)*512 + m];
    __syncthreads();
    if (t < 64){
      float v = rf[t]*rf[t];
      v += __shfl_down(v,32); v += __shfl_down(v,16); v += __shfl_down(v,8);
      v += __shfl_down(v,4);  v += __shfl_down(v,2);  v += __shfl_down(v,1);
      if (t == 0) srn2 = 1.0f / fmaxf(sqrtf(v), 1e-12f);
    }
    __syncthreads();
    if (t < 64) ws[WS_DSTN + bm*64 + t] = rf[t]*srn2;
    if (t == 0){ ws[WS_DXY + bm*2+0] = sdx; ws[WS_DXY + bm*2+1] = sdy; }
    int o = t;
    float acc = sdx*(W1[5*O1+o] - W1[7*O1+o]) + sdy*(W1[6*O1+o] - W1[8*O1+o]);
    #pragma unroll 8
    for (int c = 0; c < 64; ++c) acc += rf[c]*W1[(74+c)*O1+o];
    ws[WS_V + bm*O1 + o] = acc;
  }
}

// ---------------- K2: cos matrix + row-max (stored inverted), no atomics ----------------
__global__ __launch_bounds__(256) void k2(float* __restrict__ ws){
  int blk = blockIdx.x; int b = blk >> 9, n = blk & 511; int t = threadIdx.x;
  int bn = b*N_ + n;
  __shared__ __align__(16) float sn[64];
  __shared__ float dnt[64*65];   // +1 pad: conflict-free row reads
  __shared__ float part[4*64];
  if (t < 64) sn[t] = ws[WS_SRCN + bn*64 + t];
  float lmax = -3.4e38f;
  for (int chunk = 0; chunk < 8; ++chunk){
    __syncthreads();
    const float4* src = (const float4*)(ws + WS_DSTN + (size_t)(b*M_ + chunk*64)*64);
    #pragma unroll
    for (int i = 0; i < 4; ++i){
      float4 v = src[t + i*256];
      int base = (t + i*256)*4; int mm = base >> 6, c = base & 63;
      float* dp = &dnt[mm*65 + c];
      dp[0]=v.x; dp[1]=v.y; dp[2]=v.z; dp[3]=v.w;
    }
    __syncthreads();
    {
      int mm = t & 63, cg = t >> 6;
      const float* dr = &dnt[mm*65 + cg*16];
      const float* sr = &sn[cg*16];
      float p = 0.f;
      #pragma unroll
      for (int k = 0; k < 16; ++k) p += sr[k]*dr[k];
      part[cg*64 + mm] = p;
    }
    __syncthreads();
    if (t < 64){
      float d = part[t] + part[64+t] + part[128+t] + part[192+t];
      ws[WS_COS + bn*M_ + chunk*64 + t] = d;
      lmax = fmaxf(lmax, d);
    }
  }
  if (t < 64){
    lmax = fmaxf(lmax, __shfl_xor(lmax,32)); lmax = fmaxf(lmax, __shfl_xor(lmax,16));
    lmax = fmaxf(lmax, __shfl_xor(lmax,8));  lmax = fmaxf(lmax, __shfl_xor(lmax,4));
    lmax = fmaxf(lmax, __shfl_xor(lmax,2));  lmax = fmaxf(lmax, __shfl_xor(lmax,1));
    if (t == 0) ws[WS_RMAX + bn] = 1.0f / (lmax + 1e-6f);
  }
}

// ---------------- K2r: col maxes of COS (stored inverted), 32 blocks ----------------
__global__ __launch_bounds__(256) void k2r(float* __restrict__ ws){
  int blk = blockIdx.x;             // b = blk>>4, 32-col group = blk&15
  int b = blk >> 4; int c0 = (blk & 15)*32;
  int t = threadIdx.x;
  int col = c0 + (t & 31), seg = t >> 5;   // 8 segs x 64 rows
  float mx = -3.4e38f;
  #pragma unroll 8
  for (int i = 0; i < 64; ++i){
    int n = seg*64 + i;
    mx = fmaxf(mx, ws[WS_COS + (size_t)(b*N_ + n)*M_ + col]);
  }
  __shared__ float sred[256];
  sred[t] = mx;
  __syncthreads();
  if (t < 32){
    float m2 = sred[t];
    #pragma unroll
    for (int s2 = 1; s2 < 8; ++s2) m2 = fmaxf(m2, sred[s2*32 + t]);
    ws[WS_CMAX + b*M_ + c0 + t] = 1.0f / (m2 + 1e-10f);
  }
}

// ---------------- K3: BN1 stats via rank-structured recompute ----------------
__global__ __launch_bounds__(256) void k3(const float* __restrict__ wxyz,
    const float* __restrict__ W1, const float* __restrict__ b1, float* __restrict__ ws){
  int blk = blockIdx.x; int bn = blk >> 1, half = blk & 1; int t = threadIdx.x;
  int b = bn >> 9; int mbase = half*256;
  __shared__ float s_en[256], s_s1[256], s_s2[256];
  __shared__ float sred[512];
  float sx = wxyz[bn*3+0], sy = wxyz[bn*3+1];
  float ri = ws[WS_RMAX + bn];
  {
    int m = mbase + t;
    float2 d = *(const float2*)(ws + WS_DXY + (size_t)(b*M_+m)*2);
    float ex = sx-d.x, ey = sy-d.y;
    s_en[t] = sqrtf(ex*ex + ey*ey);
    float cv = ws[WS_COS + (size_t)bn*M_ + m];
    s_s1[t] = cv*ri;
    s_s2[t] = cv*ws[WS_CMAX + b*M_ + m];
  }
  __syncthreads();
  int o = t & 127, mh = t >> 7;
  float u  = ws[WS_U + bn*O1 + o] + b1[o];
  float w9 = W1[9*O1+o], wa = W1[138*O1+o], wb = W1[139*O1+o];
  float sum = 0.f, ssq = 0.f;
  const float* Vp = ws + WS_V + (size_t)b*M_*O1 + o;
  int lBeg = mh*128, lEnd = lBeg + 128;
  #pragma unroll 8
  for (int ml = lBeg; ml < lEnd; ++ml){
    float xv = u + Vp[(size_t)(mbase+ml)*O1] + s_en[ml]*w9 + s_s1[ml]*wa + s_s2[ml]*wb;
    sum += xv; ssq += xv*xv;
  }
  sred[mh*128 + o] = sum;
  sred[256 + mh*128 + o] = ssq;
  __syncthreads();
  if (t < 128){
    float S = sred[t] + sred[128+t];
    float Q = sred[256+t] + sred[384+t];
    int rep = blk & 63;
    atomicAdd(&ws[WS_ST1 + rep*256 + t], S);
    atomicAdd(&ws[WS_ST1 + rep*256 + 128 + t], Q);
  }
}

// ---------------- K3b: finalize BN1 -> P0; scale V by A1; pack W2 frags ----------------
__global__ __launch_bounds__(128) void k3b(const float* __restrict__ W1,
    const float* __restrict__ b1, const float* __restrict__ g1,
    const float* __restrict__ be1, const float* __restrict__ W2, float* __restrict__ ws){
  int blk = blockIdx.x; int t = threadIdx.x;
  int o = t;
  float s = 0.f, q = 0.f;
  #pragma unroll 8
  for (int r = 0; r < 64; ++r){ s += ws[WS_ST1 + r*256 + o]; q += ws[WS_ST1 + r*256 + 128 + o]; }
  float mu = s/PBIG, var = q/PBIG - mu*mu;
  float istd = rsqrtf(var + 1e-5f);
  float A1 = g1[o]*istd, C1 = be1[o] - mu*A1;
  if (blk < 1024){                       // P0[bn][o]
    int bn = blk;
    ws[WS_P0 + bn*O1 + o] = (ws[WS_U + bn*O1 + o] + b1[o])*A1 + C1;
  } else if (blk < 1040){                // V *= A1, 64 rows per block
    int r0 = (blk - 1024)*64;
    for (int r = 0; r < 64; ++r)
      ws[WS_V + (size_t)(r0 + r)*O1 + o] *= A1;
  } else {                               // scaled rank-1 cols + W2 fragment pack
    ws[WS_W9S + o]       = W1[9*O1+o]*A1;
    ws[WS_W9S + 128 + o] = W1[138*O1+o]*A1;
    ws[WS_W9S + 256 + o] = W1[139*O1+o]*A1;
    unsigned short* wf = (unsigned short*)(ws + WS_W2F);
    for (int i = t; i < 8192; i += 128){
      int j = i & 7, ll = (i >> 3) & 63, ct = (i >> 9) & 3, k0q = i >> 11;
      int oo = k0q*32 + (ll >> 4)*8 + j, c = ct*16 + (ll & 15);
      wf[i] = f2bf(W2[oo*O2 + c]);
    }
  }
}

// ---------------- K4: 2 m-chunks per block (grid 2048, 8 blocks/CU); uint4 x2 store ----
__global__ __launch_bounds__(256, 8) void k4(const float* __restrict__ wxyz,
    float* __restrict__ ws){
  int blk = blockIdx.x; int bn = blk >> 1, half = blk & 1;
  int b = bn >> 9; int t = threadIdx.x;
  __shared__ __align__(16) unsigned short wBf[8192];        // 16 KB fragment-packed W2
  __shared__ __align__(16) float p0s[128], w9s[128], was[128], wbs[128];
  __shared__ float ls[64], lq[64];
  {   // stage W2 fragments: lane-consecutive 16B (conflict-free)
    const s8v* g = (const s8v*)(ws + WS_W2F);
    s8v* l = (s8v*)wBf;
    #pragma unroll
    for (int c2 = 0; c2 < 4; ++c2) l[c2*256 + t] = g[c2*256 + t];
  }
  if (t < 64){ ls[t] = 0.f; lq[t] = 0.f; }
  if (t < 128){
    p0s[t] = ws[WS_P0 + bn*O1 + t];
    w9s[t] = ws[WS_W9S + t];
    was[t] = ws[WS_W9S + 128 + t];
    wbs[t] = ws[WS_W9S + 256 + t];
  }
  __syncthreads();
  // barrier-free from here until the final stat reduce
  int ll = t & 63, w = t >> 6, l16 = ll & 15, quad = ll >> 4;
  float sx = wxyz[bn*3+0], sy = wxyz[bn*3+1];
  float ri = ws[WS_RMAX + bn];
  float sst[4][4], sq2[4][4];
  #pragma unroll
  for (int i = 0; i < 4; ++i)
    #pragma unroll
    for (int j = 0; j < 4; ++j){ sst[i][j] = 0.f; sq2[i][j] = 0.f; }
  uint4* xf4 = (uint4*)(ws + WS_X2) + (size_t)bn*4096;
  union U8 { s8v v; unsigned u[4]; };
  #pragma unroll
  for (int mci = 0; mci < 2; ++mci){
    int mc = half*2 + mci;
    int mA = mc*128 + w*32 + l16, mB = mA + 16;
    float2 dA = *(const float2*)(ws + WS_DXY + (size_t)(b*M_+mA)*2);
    float2 dB = *(const float2*)(ws + WS_DXY + (size_t)(b*M_+mB)*2);
    float cvA = ws[WS_COS + (size_t)bn*M_ + mA], cvB = ws[WS_COS + (size_t)bn*M_ + mB];
    float ciA = ws[WS_CMAX + b*M_ + mA],         ciB = ws[WS_CMAX + b*M_ + mB];
    float exA = sx-dA.x, eyA = sy-dA.y; float en0 = sqrtf(exA*exA + eyA*eyA);
    float exB = sx-dB.x, eyB = sy-dB.y; float en1 = sqrtf(exB*exB + eyB*eyB);
    float s10 = cvA*ri, s20 = cvA*ciA;
    float s11 = cvB*ri, s21 = cvB*ciB;
    const float* vpA = ws + WS_V + (size_t)(b*M_+mA)*O1;
    const float* vpB = ws + WS_V + (size_t)(b*M_+mB)*O1;
    f4v acc[2][4];
    #pragma unroll
    for (int i = 0; i < 2; ++i)
      #pragma unroll
      for (int j = 0; j < 4; ++j) acc[i][j] = (f4v){0.f,0.f,0.f,0.f};
    #pragma unroll
    for (int k0q = 0; k0q < 4; ++k0q){
      int ko = k0q*32 + quad*8;
      f4v p0a = *(const f4v*)&p0s[ko], p0b = *(const f4v*)&p0s[ko+4];
      f4v w9a = *(const f4v*)&w9s[ko], w9b = *(const f4v*)&w9s[ko+4];
      f4v waa = *(const f4v*)&was[ko], wab = *(const f4v*)&was[ko+4];
      f4v wba = *(const f4v*)&wbs[ko], wbb = *(const f4v*)&wbs[ko+4];
      f4v vA0 = *(const f4v*)(vpA + ko), vA1 = *(const f4v*)(vpA + ko + 4);
      f4v vB0 = *(const f4v*)(vpB + ko), vB1 = *(const f4v*)(vpB + ko + 4);
      f4v zaA = relu4(p0a + vA0 + en0*w9a + s10*waa + s20*wba);
      f4v zbA = relu4(p0b + vA1 + en0*w9b + s10*wab + s20*wbb);
      f4v zaB = relu4(p0a + vB0 + en1*w9a + s11*waa + s21*wba);
      f4v zbB = relu4(p0b + vB1 + en1*w9b + s11*wab + s21*wbb);
      U8 uA, uB;
      uA.u[0] = pk_trunc(zaA[0], zaA[1]); uA.u[1] = pk_trunc(zaA[2], zaA[3]);
      uA.u[2] = pk_trunc(zbA[0], zbA[1]); uA.u[3] = pk_trunc(zbA[2], zbA[3]);
      uB.u[0] = pk_trunc(zaB[0], zaB[1]); uB.u[1] = pk_trunc(zaB[2], zaB[3]);
      uB.u[2] = pk_trunc(zbB[0], zbB[1]); uB.u[3] = pk_trunc(zbB[2], zbB[3]);
      #pragma unroll
      for (int ct = 0; ct < 4; ++ct){
        s8v bb = *(const s8v*)&wBf[((k0q*4 + ct)*64 + ll)*8];
        acc[0][ct] = __builtin_amdgcn_mfma_f32_16x16x32_bf16(bb, uA.v, acc[0][ct], 0,0,0);
        acc[1][ct] = __builtin_amdgcn_mfma_f32_16x16x32_bf16(bb, uB.v, acc[1][ct], 0,0,0);
      }
    }
    // fragment-major store, 16 B/lane: wave writes 1024 B contiguous per inst
    #pragma unroll
    for (int mt = 0; mt < 2; ++mt){
      uint4 u0, u1;
      u0.x = pk2(acc[mt][0][0], acc[mt][0][1]); u0.y = pk2(acc[mt][0][2], acc[mt][0][3]);
      u0.z = pk2(acc[mt][1][0], acc[mt][1][1]); u0.w = pk2(acc[mt][1][2], acc[mt][1][3]);
      u1.x = pk2(acc[mt][2][0], acc[mt][2][1]); u1.y = pk2(acc[mt][2][2], acc[mt][2][3]);
      u1.z = pk2(acc[mt][3][0], acc[mt][3][1]); u1.w = pk2(acc[mt][3][2], acc[mt][3][3]);
      xf4[((((mc*4 + w)*2 + mt)*2 + 0)*64) + ll] = u0;
      xf4[((((mc*4 + w)*2 + mt)*2 + 1)*64) + ll] = u1;
    }
    #pragma unroll
    for (int ct = 0; ct < 4; ++ct)
      #pragma unroll
      for (int r = 0; r < 4; ++r){
        float a0 = acc[0][ct][r], a1 = acc[1][ct][r];
        sst[ct][r] += a0 + a1;
        sq2[ct][r] += a0*a0 + a1*a1;
      }
  }
  // BN2 stat reduce: over the 16 lanes of each quad-group, then LDS
  #pragma unroll
  for (int ct = 0; ct < 4; ++ct){
    #pragma unroll
    for (int r = 0; r < 4; ++r){
      float s = sst[ct][r], q = sq2[ct][r];
      s += __shfl_xor(s,1); s += __shfl_xor(s,2); s += __shfl_xor(s,4); s += __shfl_xor(s,8);
      q += __shfl_xor(q,1); q += __shfl_xor(q,2); q += __shfl_xor(q,4); q += __shfl_xor(q,8);
      if (l16 == 0){
        atomicAdd(&ls[ct*16 + quad*4 + r], s);
        atomicAdd(&lq[ct*16 + quad*4 + r], q);
      }
    }
  }
  __syncthreads();
  int rep = blk & 63;
  if (t < 64) atomicAdd(&ws[WS_ST2 + rep*128 + t], ls[t]);
  else if (t < 128) atomicAdd(&ws[WS_ST2 + rep*128 + t], lq[t-64]);
}

// ---------------- K5: BN2 + softmax pool from uint4 fragment-major x2 ----------------
__global__ __launch_bounds__(256) void k5(const float* __restrict__ g2,
    const float* __restrict__ be2, const float* __restrict__ M1w,
    const float* __restrict__ M1b, float* __restrict__ ws){
  int bn = blockIdx.x; int t = threadIdx.x;
  __shared__ float sa2[64], sc2[64];
  __shared__ float s_mx[512];
  __shared__ float s_aw[512];
  __shared__ float red[256];
  __shared__ float part[64*65];
  __shared__ float s_att[64];
  __shared__ float sgmax, sinvS;
  if (t < 64){
    float s = 0.f, q = 0.f;
    #pragma unroll 8
    for (int r = 0; r < 64; ++r){ s += ws[WS_ST2 + r*128 + t]; q += ws[WS_ST2 + r*128 + 64 + t]; }
    float mu = s/PBIG, var = q/PBIG - mu*mu;
    float istd = rsqrtf(var + 1e-5f);
    float A2 = g2[t]*istd;
    sa2[t] = A2; sc2[t] = be2[t] - mu*A2;
  }
  __syncthreads();
  int ll = t & 63, w = t >> 6, l16 = ll & 15, quad = ll >> 4;
  const uint4* xf4 = (const uint4*)(ws + WS_X2) + (size_t)bn*4096;
  uint4 xv[4][2][2];   // [mc][mt][cp]
  #pragma unroll
  for (int mc = 0; mc < 4; ++mc)
    #pragma unroll
    for (int mt = 0; mt < 2; ++mt)
      #pragma unroll
      for (int cp = 0; cp < 2; ++cp)
        xv[mc][mt][cp] = xf4[((((mc*4 + w)*2 + mt)*2 + cp)*64) + ll];
  float a2r[4][4], c2r[4][4];
  #pragma unroll
  for (int ct = 0; ct < 4; ++ct)
    #pragma unroll
    for (int r = 0; r < 4; ++r){
      int c = ct*16 + quad*4 + r;
      a2r[ct][r] = sa2[c]; c2r[ct][r] = sc2[c];
    }
  // Pass A: per-m max over channels; 2 shuffles (across quads)
  #pragma unroll
  for (int mc = 0; mc < 4; ++mc){
    #pragma unroll
    for (int mt = 0; mt < 2; ++mt){
      float mx = 0.f;   // relu >= 0
      #pragma unroll
      for (int cp = 0; cp < 2; ++cp){
        uint4 uv = xv[mc][mt][cp];
        int c0t = 2*cp, c1t = 2*cp + 1;
        float x0 = bf2f((unsigned short)(uv.x & 0xffffu));
        float x1 = bf2f((unsigned short)(uv.x >> 16));
        float x2 = bf2f((unsigned short)(uv.y & 0xffffu));
        float x3 = bf2f((unsigned short)(uv.y >> 16));
        float x4 = bf2f((unsigned short)(uv.z & 0xffffu));
        float x5 = bf2f((unsigned short)(uv.z >> 16));
        float x6 = bf2f((unsigned short)(uv.w & 0xffffu));
        float x7 = bf2f((unsigned short)(uv.w >> 16));
        mx = fmaxf(mx, a2r[c0t][0]*x0 + c2r[c0t][0]);
        mx = fmaxf(mx, a2r[c0t][1]*x1 + c2r[c0t][1]);
        mx = fmaxf(mx, a2r[c0t][2]*x2 + c2r[c0t][2]);
        mx = fmaxf(mx, a2r[c0t][3]*x3 + c2r[c0t][3]);
        mx = fmaxf(mx, a2r[c1t][0]*x4 + c2r[c1t][0]);
        mx = fmaxf(mx, a2r[c1t][1]*x5 + c2r[c1t][1]);
        mx = fmaxf(mx, a2r[c1t][2]*x6 + c2r[c1t][2]);
        mx = fmaxf(mx, a2r[c1t][3]*x7 + c2r[c1t][3]);
      }
      mx = fmaxf(mx, __shfl_xor(mx,16));
      mx = fmaxf(mx, __shfl_xor(mx,32));
      if (quad == 0) s_mx[mc*128 + w*32 + mt*16 + l16] = mx;
    }
  }
  __syncthreads();
  red[t] = fmaxf(s_mx[t], s_mx[t+256]);
  __syncthreads();
  for (int s = 128; s > 0; s >>= 1){ if (t < s) red[t] = fmaxf(red[t], red[t+s]); __syncthreads(); }
  if (t == 0) sgmax = red[0];
  __syncthreads();
  float e0 = expf(s_mx[t] - sgmax), e1 = expf(s_mx[t+256] - sgmax);
  s_aw[t] = e0; s_aw[t+256] = e1;
  red[t] = e0 + e1;
  __syncthreads();
  for (int s = 128; s > 0; s >>= 1){ if (t < s) red[t] += red[t+s]; __syncthreads(); }
  if (t == 0) sinvS = 1.0f / red[0];
  __syncthreads();
  // Pass C: weighted sum (y recomputed from registers)
  float acc[4][4];
  #pragma unroll
  for (int ct = 0; ct < 4; ++ct)
    #pragma unroll
    for (int r = 0; r < 4; ++r) acc[ct][r] = 0.f;
  #pragma unroll
  for (int mc = 0; mc < 4; ++mc){
    #pragma unroll
    for (int mt = 0; mt < 2; ++mt){
      float aw = s_aw[mc*128 + w*32 + mt*16 + l16];
      #pragma unroll
      for (int cp = 0; cp < 2; ++cp){
        uint4 uv = xv[mc][mt][cp];
        int c0t = 2*cp, c1t = 2*cp + 1;
        float x0 = bf2f((unsigned short)(uv.x & 0xffffu));
        float x1 = bf2f((unsigned short)(uv.x >> 16));
        float x2 = bf2f((unsigned short)(uv.y & 0xffffu));
        float x3 = bf2f((unsigned short)(uv.y >> 16));
        float x4 = bf2f((unsigned short)(uv.z & 0xffffu));
        float x5 = bf2f((unsigned short)(uv.z >> 16));
        float x6 = bf2f((unsigned short)(uv.w & 0xffffu));
        float x7 = bf2f((unsigned short)(uv.w >> 16));
        acc[c0t][0] += aw*fmaxf(a2r[c0t][0]*x0 + c2r[c0t][0], 0.f);
        acc[c0t][1] += aw*fmaxf(a2r[c0t][1]*x1 + c2r[c0t][1], 0.f);
        acc[c0t][2] += aw*fmaxf(a2r[c0t][2]*x2 + c2r[c0t][2], 0.f);
        acc[c0t][3] += aw*fmaxf(a2r[c0t][3]*x3 + c2r[c0t][3], 0.f);
        acc[c1t][0] += aw*fmaxf(a2r[c1t][0]*x4 + c2r[c1t][0], 0.f);
        acc[c1t][1] += aw*fmaxf(a2r[c1t][1]*x5 + c2r[c1t][1], 0.f);
        acc[c1t][2] += aw*fmaxf(a2r[c1t][2]*x6 + c2r[c1t][2], 0.f);
        acc[c1t][3] += aw*fmaxf(a2r[c1t][3]*x7 + c2r[c1t][3], 0.f);
      }
    }
  }
  int row = w*16 + l16;
  #pragma unroll
  for (int ct = 0; ct < 4; ++ct)
    #pragma unroll
    for (int r = 0; r < 4; ++r)
      part[row*65 + ct*16 + quad*4 + r] = acc[ct][r];
  __syncthreads();
  if (t < 64){
    float a = 0.f;
    #pragma unroll 8
    for (int r = 0; r < 64; ++r) a += part[r*65 + t];
    s_att[t] = a * sinvS;
  }
  __syncthreads();
  if (t < 32){
    float z = M1b[t];
    #pragma unroll 8
    for (int c = 0; c < 64; ++c) z += s_att[c]*M1w[c*32 + t];
    ws[WS_Z + bn*32 + t] = z;
    int rep = bn & 63;
    atomicAdd(&ws[WS_ST3 + rep*64 + t], z);
    atomicAdd(&ws[WS_ST3 + rep*64 + 32 + t], z*z);
  }
}

// ---------------- K6: BN3 + head L2 -> logits ----------------
__global__ __launch_bounds__(256) void k6(const float* __restrict__ M1g,
    const float* __restrict__ M1be, const float* __restrict__ M2w,
    const float* __restrict__ M2b, const float* __restrict__ ws, float* __restrict__ out){
  int t = threadIdx.x; int s = blockIdx.x*256 + t;
  __shared__ float sa3[32], sc3[32];
  if (t < 32){
    float su = 0.f, q = 0.f;
    #pragma unroll 8
    for (int r = 0; r < 64; ++r){ su += ws[WS_ST3 + r*64 + t]; q += ws[WS_ST3 + r*64 + 32 + t]; }
    float mu = su/P3, var = q/P3 - mu*mu;
    float istd = rsqrtf(var + 1e-5f);
    float A3 = M1g[t]*istd;
    sa3[t] = A3; sc3[t] = M1be[t] - mu*A3;
  }
  __syncthreads();
  float a0 = M2b[0], a1 = M2b[1];
  #pragma unroll
  for (int j = 0; j < 32; ++j){
    float y = fmaxf(ws[WS_Z + s*32 + j]*sa3[j] + sc3[j], 0.f);
    a0 += y*M2w[j*2+0]; a1 += y*M2w[j*2+1];
  }
  out[s*2+0] = a0; out[s*2+1] = a1;
}

extern "C" void kernel_launch(void* const* d_in, const int* in_sizes, int n_in,
                              void* d_out, int out_size, void* d_ws, size_t ws_size,
                              hipStream_t stream){
  const float* wxyz = (const float*)d_in[0];
  const float* wpts = (const float*)d_in[1];
  const float* rf3  = (const float*)d_in[2];
  const float* rf3i = (const float*)d_in[3];
  const float* lz   = (const float*)d_in[4];
  const float* W1   = (const float*)d_in[5];
  const float* b1   = (const float*)d_in[6];
  const float* g1   = (const float*)d_in[7];
  const float* be1  = (const float*)d_in[8];
  const float* W2   = (const float*)d_in[9];
  const float* g2   = (const float*)d_in[11];
  const float* be2  = (const float*)d_in[12];
  const float* M1w  = (const float*)d_in[13];
  const float* M1b  = (const float*)d_in[14];
  const float* M1g  = (const float*)d_in[15];
  const float* M1be = (const float*)d_in[16];
  const float* M2w  = (const float*)d_in[17];
  const float* M2b  = (const float*)d_in[18];
  float* ws  = (float*)d_ws;
  float* out = (float*)d_out;
  // zero BN stat accumulators (ST1+ST2+ST3 contiguous: 28672 floats)
  hipMemsetAsync(ws + WS_ST1, 0, 28672*sizeof(float), stream);
  k1 <<<2048,128,0,stream>>>(wxyz, wpts, lz, rf3, rf3i, W1, ws);
  k2 <<<1024,256,0,stream>>>(ws);
  k2r<<<32,256,0,stream>>>(ws);
  k3 <<<2048,256,0,stream>>>(wxyz, W1, b1, ws);
  k3b<<<1041,128,0,stream>>>(W1, b1, g1, be1, W2, ws);
  k4 <<<2048,256,0,stream>>>(wxyz, ws);
  k5 <<<1024,256,0,stream>>>(g2, be2, M1w, M1b, ws);
  k6 <<<4,256,0,stream>>>(M1g, M1be, M2w, M2b, ws, out);
}

// Round 7
// 232.644 us; speedup vs baseline: 1.3338x; 1.3338x over previous
//
#include <hip/hip_runtime.h>
#include <hip/hip_bf16.h>

// Problem constants (B,N,H,W,C) = (2,512,16,32,64)
#define B_ 2
#define N_ 512
#define M_ 512
#define C_ 64
#define O1 128
#define O2 64
#define O3 32
#define PBIG 524288.0f   // B*N*M samples for BN1/BN2
#define P3   1024.0f     // B*N samples for BN3

typedef short s8v __attribute__((ext_vector_type(8)));   // 8 bf16 (4 VGPRs)
typedef float f4v __attribute__((ext_vector_type(4)));   // MFMA accumulator

// ---- workspace layout (float-element offsets) ----
#define WS_SRCN 0        //  [B][N][64]  (dead after k2 -> reused as WS_P0)
#define WS_DSTN 65536    //  [B][M][64]  (dead after k2 -> reused as WS_P0)
#define WS_P0   0        //  [B*N][128] BN1-folded per-(b,n) part (k3b)
#define WS_U    131072   //  [B][N][128] (dead after k3b -> reused as WS_Z)
#define WS_Z    131072   //  [B][N][32]  (k5 -> k6)
#define WS_V    262144   //  [B][M][128] (scaled by A1 in k3b, in place)
#define WS_DXY  393216   //  [B][M][2]
#define WS_COS  395264   //  [B][N][M]  -> ends 919552
#define WS_RMAX 919552   //  [B*N] INVERSE row max: 1/(max+1e-6)
#define WS_ST1  920576   //  [64][256] BN1 partials -> 936960
#define WS_ST2  936960   //  [64][128] BN2 partials -> 945152
#define WS_ST3  945152   //  [64][64]  BN3 partials -> 949248
#define WS_CMAX 949248   //  [B*M] INVERSE col max: 1/(max+1e-10)
#define WS_W2F  950272   //  bf16 [8192] fragment-packed W2 (k3b -> k4)
#define WS_W9S  954368   //  [3][128] A1-scaled W1 rank-1 columns
#define WS_X2   961536   //  bf16 fragment-major [B*N][4096] uint4 (64 KB per bn)

__device__ __forceinline__ unsigned short f2bf(float f){
  unsigned u = __float_as_uint(f);
  unsigned r = (u + 0x7fffu + ((u >> 16) & 1u)) >> 16;   // RNE
  return (unsigned short)r;
}
__device__ __forceinline__ float bf2f(unsigned short h){
  return __uint_as_float(((unsigned)h) << 16);
}
__device__ __forceinline__ unsigned pk2(float lo, float hi){
  return (unsigned)f2bf(lo) | ((unsigned)f2bf(hi) << 16);
}
// pack two f32 -> bf16x2 by truncation: one v_perm_b32 (used for MFMA inputs)
__device__ __forceinline__ unsigned pk_trunc(float lo, float hi){
  return __builtin_amdgcn_perm(__float_as_uint(hi), __float_as_uint(lo), 0x07060302u);
}
__device__ __forceinline__ f4v relu4(f4v z){
  z[0] = fmaxf(z[0], 0.f); z[1] = fmaxf(z[1], 0.f);
  z[2] = fmaxf(z[2], 0.f); z[3] = fmaxf(z[3], 0.f);
  return z;
}

// ---------------- K1: fused per-n (blk<1024) and per-m precompute ----------------
__global__ __launch_bounds__(128) void k1(const float* __restrict__ wxyz,
    const float* __restrict__ wpts, const float* __restrict__ lz,
    const float* __restrict__ rf3, const float* __restrict__ rf3i,
    const float* __restrict__ W1, float* __restrict__ ws){
  int t = threadIdx.x;
  if (blockIdx.x < 1024){
    int blk = blockIdx.x; int b = blk >> 9, n = blk & 511;
    int bn = b*N_ + n;
    __shared__ float wp[64]; __shared__ float sxyz[3]; __shared__ float slz; __shared__ float srn;
    if (t < 64) wp[t] = wpts[bn*64 + t];
    if (t >= 64 && t < 67) sxyz[t-64] = wxyz[bn*3 + (t-64)];
    if (t == 67) slz = lz[bn];
    __syncthreads();
    if (t < 64){
      float v = wp[t]*wp[t];
      v += __shfl_down(v,32); v += __shfl_down(v,16); v += __shfl_down(v,8);
      v += __shfl_down(v,4);  v += __shfl_down(v,2);  v += __shfl_down(v,1);
      if (t == 0) srn = 1.0f / fmaxf(sqrtf(v), 1e-12f);
    }
    __syncthreads();
    if (t < 64) ws[WS_SRCN + bn*64 + t] = wp[t]*srn;
    int o = t;
    float x = sxyz[0], y = sxyz[1], z = sxyz[2], l = slz;
    float acc = x*l*W1[0*O1+o] + y*l*W1[1*O1+o] + z*l*W1[2*O1+o]
              + wp[0]*W1[3*O1+o] + wp[1]*W1[4*O1+o]
              + x*W1[7*O1+o] + y*W1[8*O1+o];
    #pragma unroll 8
    for (int c = 0; c < 64; ++c) acc += wp[c]*W1[(10+c)*O1+o];
    ws[WS_U + bn*O1 + o] = acc;
  } else {
    int blk = blockIdx.x - 1024; int b = blk >> 9, m = blk & 511;
    int bm = b*M_ + m;
    __shared__ float rf[64]; __shared__ float sdx, sdy, srn2;
    if (t < 64) rf[t] = rf3[(b*64 + t)*512 + m];
    if (t == 64) sdx = rf3i[(b*3 + 0)*512 + m];
    if (t == 65) sdy = rf3i[(b*3 + 1)*512 + m];
    __syncthreads();
    if (t < 64){
      float v = rf[t]*rf[t];
      v += __shfl_down(v,32); v += __shfl_down(v,16); v += __shfl_down(v,8);
      v += __shfl_down(v,4);  v += __shfl_down(v,2);  v += __shfl_down(v,1);
      if (t == 0) srn2 = 1.0f / fmaxf(sqrtf(v), 1e-12f);
    }
    __syncthreads();
    if (t < 64) ws[WS_DSTN + bm*64 + t] = rf[t]*srn2;
    if (t == 0){ ws[WS_DXY + bm*2+0] = sdx; ws[WS_DXY + bm*2+1] = sdy; }
    int o = t;
    float acc = sdx*(W1[5*O1+o] - W1[7*O1+o]) + sdy*(W1[6*O1+o] - W1[8*O1+o]);
    #pragma unroll 8
    for (int c = 0; c < 64; ++c) acc += rf[c]*W1[(74+c)*O1+o];
    ws[WS_V + bm*O1 + o] = acc;
  }
}

// ---------------- K2: cos matrix + row-max (stored inverted), no atomics ----------------
__global__ __launch_bounds__(256) void k2(float* __restrict__ ws){
  int blk = blockIdx.x; int b = blk >> 9, n = blk & 511; int t = threadIdx.x;
  int bn = b*N_ + n;
  __shared__ __align__(16) float sn[64];
  __shared__ float dnt[64*65];   // +1 pad: conflict-free row reads
  __shared__ float part[4*64];
  if (t < 64) sn[t] = ws[WS_SRCN + bn*64 + t];
  float lmax = -3.4e38f;
  for (int chunk = 0; chunk < 8; ++chunk){
    __syncthreads();
    const float4* src = (const float4*)(ws + WS_DSTN + (size_t)(b*M_ + chunk*64)*64);
    #pragma unroll
    for (int i = 0; i < 4; ++i){
      float4 v = src[t + i*256];
      int base = (t + i*256)*4; int mm = base >> 6, c = base & 63;
      float* dp = &dnt[mm*65 + c];
      dp[0]=v.x; dp[1]=v.y; dp[2]=v.z; dp[3]=v.w;
    }
    __syncthreads();
    {
      int mm = t & 63, cg = t >> 6;
      const float* dr = &dnt[mm*65 + cg*16];
      const float* sr = &sn[cg*16];
      float p = 0.f;
      #pragma unroll
      for (int k = 0; k < 16; ++k) p += sr[k]*dr[k];
      part[cg*64 + mm] = p;
    }
    __syncthreads();
    if (t < 64){
      float d = part[t] + part[64+t] + part[128+t] + part[192+t];
      ws[WS_COS + bn*M_ + chunk*64 + t] = d;
      lmax = fmaxf(lmax, d);
    }
  }
  if (t < 64){
    lmax = fmaxf(lmax, __shfl_xor(lmax,32)); lmax = fmaxf(lmax, __shfl_xor(lmax,16));
    lmax = fmaxf(lmax, __shfl_xor(lmax,8));  lmax = fmaxf(lmax, __shfl_xor(lmax,4));
    lmax = fmaxf(lmax, __shfl_xor(lmax,2));  lmax = fmaxf(lmax, __shfl_xor(lmax,1));
    if (t == 0) ws[WS_RMAX + bn] = 1.0f / (lmax + 1e-6f);
  }
}

// ---------------- K2r: col maxes of COS (stored inverted), 32 blocks ----------------
__global__ __launch_bounds__(256) void k2r(float* __restrict__ ws){
  int blk = blockIdx.x;             // b = blk>>4, 32-col group = blk&15
  int b = blk >> 4; int c0 = (blk & 15)*32;
  int t = threadIdx.x;
  int col = c0 + (t & 31), seg = t >> 5;   // 8 segs x 64 rows
  float mx = -3.4e38f;
  #pragma unroll 8
  for (int i = 0; i < 64; ++i){
    int n = seg*64 + i;
    mx = fmaxf(mx, ws[WS_COS + (size_t)(b*N_ + n)*M_ + col]);
  }
  __shared__ float sred[256];
  sred[t] = mx;
  __syncthreads();
  if (t < 32){
    float m2 = sred[t];
    #pragma unroll
    for (int s2 = 1; s2 < 8; ++s2) m2 = fmaxf(m2, sred[s2*32 + t]);
    ws[WS_CMAX + b*M_ + c0 + t] = 1.0f / (m2 + 1e-10f);
  }
}

// ---------------- K3: BN1 stats via rank-structured recompute ----------------
__global__ __launch_bounds__(256) void k3(const float* __restrict__ wxyz,
    const float* __restrict__ W1, const float* __restrict__ b1, float* __restrict__ ws){
  int blk = blockIdx.x; int bn = blk >> 1, half = blk & 1; int t = threadIdx.x;
  int b = bn >> 9; int mbase = half*256;
  __shared__ float s_en[256], s_s1[256], s_s2[256];
  __shared__ float sred[512];
  float sx = wxyz[bn*3+0], sy = wxyz[bn*3+1];
  float ri = ws[WS_RMAX + bn];
  {
    int m = mbase + t;
    float2 d = *(const float2*)(ws + WS_DXY + (size_t)(b*M_+m)*2);
    float ex = sx-d.x, ey = sy-d.y;
    s_en[t] = sqrtf(ex*ex + ey*ey);
    float cv = ws[WS_COS + (size_t)bn*M_ + m];
    s_s1[t] = cv*ri;
    s_s2[t] = cv*ws[WS_CMAX + b*M_ + m];
  }
  __syncthreads();
  int o = t & 127, mh = t >> 7;
  float u  = ws[WS_U + bn*O1 + o] + b1[o];
  float w9 = W1[9*O1+o], wa = W1[138*O1+o], wb = W1[139*O1+o];
  float sum = 0.f, ssq = 0.f;
  const float* Vp = ws + WS_V + (size_t)b*M_*O1 + o;
  int lBeg = mh*128, lEnd = lBeg + 128;
  #pragma unroll 8
  for (int ml = lBeg; ml < lEnd; ++ml){
    float xv = u + Vp[(size_t)(mbase+ml)*O1] + s_en[ml]*w9 + s_s1[ml]*wa + s_s2[ml]*wb;
    sum += xv; ssq += xv*xv;
  }
  sred[mh*128 + o] = sum;
  sred[256 + mh*128 + o] = ssq;
  __syncthreads();
  if (t < 128){
    float S = sred[t] + sred[128+t];
    float Q = sred[256+t] + sred[384+t];
    int rep = blk & 63;
    atomicAdd(&ws[WS_ST1 + rep*256 + t], S);
    atomicAdd(&ws[WS_ST1 + rep*256 + 128 + t], Q);
  }
}

// ---------------- K3b: finalize BN1 -> P0; scale V by A1; pack W2 frags ----------------
__global__ __launch_bounds__(128) void k3b(const float* __restrict__ W1,
    const float* __restrict__ b1, const float* __restrict__ g1,
    const float* __restrict__ be1, const float* __restrict__ W2, float* __restrict__ ws){
  int blk = blockIdx.x; int t = threadIdx.x;
  int o = t;
  float s = 0.f, q = 0.f;
  #pragma unroll 8
  for (int r = 0; r < 64; ++r){ s += ws[WS_ST1 + r*256 + o]; q += ws[WS_ST1 + r*256 + 128 + o]; }
  float mu = s/PBIG, var = q/PBIG - mu*mu;
  float istd = rsqrtf(var + 1e-5f);
  float A1 = g1[o]*istd, C1 = be1[o] - mu*A1;
  if (blk < 1024){                       // P0[bn][o]
    int bn = blk;
    ws[WS_P0 + bn*O1 + o] = (ws[WS_U + bn*O1 + o] + b1[o])*A1 + C1;
  } else if (blk < 1040){                // V *= A1, 64 rows per block
    int r0 = (blk - 1024)*64;
    for (int r = 0; r < 64; ++r)
      ws[WS_V + (size_t)(r0 + r)*O1 + o] *= A1;
  } else {                               // scaled rank-1 cols + W2 fragment pack
    ws[WS_W9S + o]       = W1[9*O1+o]*A1;
    ws[WS_W9S + 128 + o] = W1[138*O1+o]*A1;
    ws[WS_W9S + 256 + o] = W1[139*O1+o]*A1;
    unsigned short* wf = (unsigned short*)(ws + WS_W2F);
    for (int i = t; i < 8192; i += 128){
      int j = i & 7, ll = (i >> 3) & 63, ct = (i >> 9) & 3, k0q = i >> 11;
      int oo = k0q*32 + (ll >> 4)*8 + j, c = ct*16 + (ll & 15);
      wf[i] = f2bf(W2[oo*O2 + c]);
    }
  }
}

// ---------------- K4: 2 m-chunks per block (grid 2048); uint4 x2 store; no spill ----
// block=256, min 4 waves/EU: VGPR cap ~128 -> compiler uses ~64-80, NO scratch spill.
// (256,8) forced VGPR=32 and spilled: WRITE_SIZE 280MB, dur 125us. Keep 4.
__global__ __launch_bounds__(256, 4) void k4(const float* __restrict__ wxyz,
    float* __restrict__ ws){
  int blk = blockIdx.x; int bn = blk >> 1, half = blk & 1;
  int b = bn >> 9; int t = threadIdx.x;
  __shared__ __align__(16) unsigned short wBf[8192];        // 16 KB fragment-packed W2
  __shared__ __align__(16) float p0s[128], w9s[128], was[128], wbs[128];
  __shared__ float ls[64], lq[64];
  {   // stage W2 fragments: lane-consecutive 16B (conflict-free)
    const s8v* g = (const s8v*)(ws + WS_W2F);
    s8v* l = (s8v*)wBf;
    #pragma unroll
    for (int c2 = 0; c2 < 4; ++c2) l[c2*256 + t] = g[c2*256 + t];
  }
  if (t < 64){ ls[t] = 0.f; lq[t] = 0.f; }
  if (t < 128){
    p0s[t] = ws[WS_P0 + bn*O1 + t];
    w9s[t] = ws[WS_W9S + t];
    was[t] = ws[WS_W9S + 128 + t];
    wbs[t] = ws[WS_W9S + 256 + t];
  }
  __syncthreads();
  // barrier-free from here until the final stat reduce
  int ll = t & 63, w = t >> 6, l16 = ll & 15, quad = ll >> 4;
  float sx = wxyz[bn*3+0], sy = wxyz[bn*3+1];
  float ri = ws[WS_RMAX + bn];
  float sst[4][4], sq2[4][4];
  #pragma unroll
  for (int i = 0; i < 4; ++i)
    #pragma unroll
    for (int j = 0; j < 4; ++j){ sst[i][j] = 0.f; sq2[i][j] = 0.f; }
  uint4* xf4 = (uint4*)(ws + WS_X2) + (size_t)bn*4096;
  union U8 { s8v v; unsigned u[4]; };
  #pragma unroll
  for (int mci = 0; mci < 2; ++mci){
    int mc = half*2 + mci;
    int mA = mc*128 + w*32 + l16, mB = mA + 16;
    float2 dA = *(const float2*)(ws + WS_DXY + (size_t)(b*M_+mA)*2);
    float2 dB = *(const float2*)(ws + WS_DXY + (size_t)(b*M_+mB)*2);
    float cvA = ws[WS_COS + (size_t)bn*M_ + mA], cvB = ws[WS_COS + (size_t)bn*M_ + mB];
    float ciA = ws[WS_CMAX + b*M_ + mA],         ciB = ws[WS_CMAX + b*M_ + mB];
    float exA = sx-dA.x, eyA = sy-dA.y; float en0 = sqrtf(exA*exA + eyA*eyA);
    float exB = sx-dB.x, eyB = sy-dB.y; float en1 = sqrtf(exB*exB + eyB*eyB);
    float s10 = cvA*ri, s20 = cvA*ciA;
    float s11 = cvB*ri, s21 = cvB*ciB;
    const float* vpA = ws + WS_V + (size_t)(b*M_+mA)*O1;
    const float* vpB = ws + WS_V + (size_t)(b*M_+mB)*O1;
    f4v acc[2][4];
    #pragma unroll
    for (int i = 0; i < 2; ++i)
      #pragma unroll
      for (int j = 0; j < 4; ++j) acc[i][j] = (f4v){0.f,0.f,0.f,0.f};
    #pragma unroll
    for (int k0q = 0; k0q < 4; ++k0q){
      int ko = k0q*32 + quad*8;
      f4v p0a = *(const f4v*)&p0s[ko], p0b = *(const f4v*)&p0s[ko+4];
      f4v w9a = *(const f4v*)&w9s[ko], w9b = *(const f4v*)&w9s[ko+4];
      f4v waa = *(const f4v*)&was[ko], wab = *(const f4v*)&was[ko+4];
      f4v wba = *(const f4v*)&wbs[ko], wbb = *(const f4v*)&wbs[ko+4];
      f4v vA0 = *(const f4v*)(vpA + ko), vA1 = *(const f4v*)(vpA + ko + 4);
      f4v vB0 = *(const f4v*)(vpB + ko), vB1 = *(const f4v*)(vpB + ko + 4);
      f4v zaA = relu4(p0a + vA0 + en0*w9a + s10*waa + s20*wba);
      f4v zbA = relu4(p0b + vA1 + en0*w9b + s10*wab + s20*wbb);
      f4v zaB = relu4(p0a + vB0 + en1*w9a + s11*waa + s21*wba);
      f4v zbB = relu4(p0b + vB1 + en1*w9b + s11*wab + s21*wbb);
      U8 uA, uB;
      uA.u[0] = pk_trunc(zaA[0], zaA[1]); uA.u[1] = pk_trunc(zaA[2], zaA[3]);
      uA.u[2] = pk_trunc(zbA[0], zbA[1]); uA.u[3] = pk_trunc(zbA[2], zbA[3]);
      uB.u[0] = pk_trunc(zaB[0], zaB[1]); uB.u[1] = pk_trunc(zaB[2], zaB[3]);
      uB.u[2] = pk_trunc(zbB[0], zbB[1]); uB.u[3] = pk_trunc(zbB[2], zbB[3]);
      #pragma unroll
      for (int ct = 0; ct < 4; ++ct){
        s8v bb = *(const s8v*)&wBf[((k0q*4 + ct)*64 + ll)*8];
        acc[0][ct] = __builtin_amdgcn_mfma_f32_16x16x32_bf16(bb, uA.v, acc[0][ct], 0,0,0);
        acc[1][ct] = __builtin_amdgcn_mfma_f32_16x16x32_bf16(bb, uB.v, acc[1][ct], 0,0,0);
      }
    }
    // fragment-major store, 16 B/lane: wave writes 1024 B contiguous per inst
    #pragma unroll
    for (int mt = 0; mt < 2; ++mt){
      uint4 u0, u1;
      u0.x = pk2(acc[mt][0][0], acc[mt][0][1]); u0.y = pk2(acc[mt][0][2], acc[mt][0][3]);
      u0.z = pk2(acc[mt][1][0], acc[mt][1][1]); u0.w = pk2(acc[mt][1][2], acc[mt][1][3]);
      u1.x = pk2(acc[mt][2][0], acc[mt][2][1]); u1.y = pk2(acc[mt][2][2], acc[mt][2][3]);
      u1.z = pk2(acc[mt][3][0], acc[mt][3][1]); u1.w = pk2(acc[mt][3][2], acc[mt][3][3]);
      xf4[((((mc*4 + w)*2 + mt)*2 + 0)*64) + ll] = u0;
      xf4[((((mc*4 + w)*2 + mt)*2 + 1)*64) + ll] = u1;
    }
    #pragma unroll
    for (int ct = 0; ct < 4; ++ct)
      #pragma unroll
      for (int r = 0; r < 4; ++r){
        float a0 = acc[0][ct][r], a1 = acc[1][ct][r];
        sst[ct][r] += a0 + a1;
        sq2[ct][r] += a0*a0 + a1*a1;
      }
  }
  // BN2 stat reduce: over the 16 lanes of each quad-group, then LDS
  #pragma unroll
  for (int ct = 0; ct < 4; ++ct){
    #pragma unroll
    for (int r = 0; r < 4; ++r){
      float s = sst[ct][r], q = sq2[ct][r];
      s += __shfl_xor(s,1); s += __shfl_xor(s,2); s += __shfl_xor(s,4); s += __shfl_xor(s,8);
      q += __shfl_xor(q,1); q += __shfl_xor(q,2); q += __shfl_xor(q,4); q += __shfl_xor(q,8);
      if (l16 == 0){
        atomicAdd(&ls[ct*16 + quad*4 + r], s);
        atomicAdd(&lq[ct*16 + quad*4 + r], q);
      }
    }
  }
  __syncthreads();
  int rep = blk & 63;
  if (t < 64) atomicAdd(&ws[WS_ST2 + rep*128 + t], ls[t]);
  else if (t < 128) atomicAdd(&ws[WS_ST2 + rep*128 + t], lq[t-64]);
}

// ---------------- K5: BN2 + softmax pool from uint4 fragment-major x2 ----------------
__global__ __launch_bounds__(256) void k5(const float* __restrict__ g2,
    const float* __restrict__ be2, const float* __restrict__ M1w,
    const float* __restrict__ M1b, float* __restrict__ ws){
  int bn = blockIdx.x; int t = threadIdx.x;
  __shared__ float sa2[64], sc2[64];
  __shared__ float s_mx[512];
  __shared__ float s_aw[512];
  __shared__ float red[256];
  __shared__ float part[64*65];
  __shared__ float s_att[64];
  __shared__ float sgmax, sinvS;
  if (t < 64){
    float s = 0.f, q = 0.f;
    #pragma unroll 8
    for (int r = 0; r < 64; ++r){ s += ws[WS_ST2 + r*128 + t]; q += ws[WS_ST2 + r*128 + 64 + t]; }
    float mu = s/PBIG, var = q/PBIG - mu*mu;
    float istd = rsqrtf(var + 1e-5f);
    float A2 = g2[t]*istd;
    sa2[t] = A2; sc2[t] = be2[t] - mu*A2;
  }
  __syncthreads();
  int ll = t & 63, w = t >> 6, l16 = ll & 15, quad = ll >> 4;
  const uint4* xf4 = (const uint4*)(ws + WS_X2) + (size_t)bn*4096;
  uint4 xv[4][2][2];   // [mc][mt][cp]
  #pragma unroll
  for (int mc = 0; mc < 4; ++mc)
    #pragma unroll
    for (int mt = 0; mt < 2; ++mt)
      #pragma unroll
      for (int cp = 0; cp < 2; ++cp)
        xv[mc][mt][cp] = xf4[((((mc*4 + w)*2 + mt)*2 + cp)*64) + ll];
  float a2r[4][4], c2r[4][4];
  #pragma unroll
  for (int ct = 0; ct < 4; ++ct)
    #pragma unroll
    for (int r = 0; r < 4; ++r){
      int c = ct*16 + quad*4 + r;
      a2r[ct][r] = sa2[c]; c2r[ct][r] = sc2[c];
    }
  // Pass A: per-m max over channels; 2 shuffles (across quads)
  #pragma unroll
  for (int mc = 0; mc < 4; ++mc){
    #pragma unroll
    for (int mt = 0; mt < 2; ++mt){
      float mx = 0.f;   // relu >= 0
      #pragma unroll
      for (int cp = 0; cp < 2; ++cp){
        uint4 uv = xv[mc][mt][cp];
        int c0t = 2*cp, c1t = 2*cp + 1;
        float x0 = bf2f((unsigned short)(uv.x & 0xffffu));
        float x1 = bf2f((unsigned short)(uv.x >> 16));
        float x2 = bf2f((unsigned short)(uv.y & 0xffffu));
        float x3 = bf2f((unsigned short)(uv.y >> 16));
        float x4 = bf2f((unsigned short)(uv.z & 0xffffu));
        float x5 = bf2f((unsigned short)(uv.z >> 16));
        float x6 = bf2f((unsigned short)(uv.w & 0xffffu));
        float x7 = bf2f((unsigned short)(uv.w >> 16));
        mx = fmaxf(mx, a2r[c0t][0]*x0 + c2r[c0t][0]);
        mx = fmaxf(mx, a2r[c0t][1]*x1 + c2r[c0t][1]);
        mx = fmaxf(mx, a2r[c0t][2]*x2 + c2r[c0t][2]);
        mx = fmaxf(mx, a2r[c0t][3]*x3 + c2r[c0t][3]);
        mx = fmaxf(mx, a2r[c1t][0]*x4 + c2r[c1t][0]);
        mx = fmaxf(mx, a2r[c1t][1]*x5 + c2r[c1t][1]);
        mx = fmaxf(mx, a2r[c1t][2]*x6 + c2r[c1t][2]);
        mx = fmaxf(mx, a2r[c1t][3]*x7 + c2r[c1t][3]);
      }
      mx = fmaxf(mx, __shfl_xor(mx,16));
      mx = fmaxf(mx, __shfl_xor(mx,32));
      if (quad == 0) s_mx[mc*128 + w*32 + mt*16 + l16] = mx;
    }
  }
  __syncthreads();
  red[t] = fmaxf(s_mx[t], s_mx[t+256]);
  __syncthreads();
  for (int s = 128; s > 0; s >>= 1){ if (t < s) red[t] = fmaxf(red[t], red[t+s]); __syncthreads(); }
  if (t == 0) sgmax = red[0];
  __syncthreads();
  float e0 = expf(s_mx[t] - sgmax), e1 = expf(s_mx[t+256] - sgmax);
  s_aw[t] = e0; s_aw[t+256] = e1;
  red[t] = e0 + e1;
  __syncthreads();
  for (int s = 128; s > 0; s >>= 1){ if (t < s) red[t] += red[t+s]; __syncthreads(); }
  if (t == 0) sinvS = 1.0f / red[0];
  __syncthreads();
  // Pass C: weighted sum (y recomputed from registers)
  float acc[4][4];
  #pragma unroll
  for (int ct = 0; ct < 4; ++ct)
    #pragma unroll
    for (int r = 0; r < 4; ++r) acc[ct][r] = 0.f;
  #pragma unroll
  for (int mc = 0; mc < 4; ++mc){
    #pragma unroll
    for (int mt = 0; mt < 2; ++mt){
      float aw = s_aw[mc*128 + w*32 + mt*16 + l16];
      #pragma unroll
      for (int cp = 0; cp < 2; ++cp){
        uint4 uv = xv[mc][mt][cp];
        int c0t = 2*cp, c1t = 2*cp + 1;
        float x0 = bf2f((unsigned short)(uv.x & 0xffffu));
        float x1 = bf2f((unsigned short)(uv.x >> 16));
        float x2 = bf2f((unsigned short)(uv.y & 0xffffu));
        float x3 = bf2f((unsigned short)(uv.y >> 16));
        float x4 = bf2f((unsigned short)(uv.z & 0xffffu));
        float x5 = bf2f((unsigned short)(uv.z >> 16));
        float x6 = bf2f((unsigned short)(uv.w & 0xffffu));
        float x7 = bf2f((unsigned short)(uv.w >> 16));
        acc[c0t][0] += aw*fmaxf(a2r[c0t][0]*x0 + c2r[c0t][0], 0.f);
        acc[c0t][1] += aw*fmaxf(a2r[c0t][1]*x1 + c2r[c0t][1], 0.f);
        acc[c0t][2] += aw*fmaxf(a2r[c0t][2]*x2 + c2r[c0t][2], 0.f);
        acc[c0t][3] += aw*fmaxf(a2r[c0t][3]*x3 + c2r[c0t][3], 0.f);
        acc[c1t][0] += aw*fmaxf(a2r[c1t][0]*x4 + c2r[c1t][0], 0.f);
        acc[c1t][1] += aw*fmaxf(a2r[c1t][1]*x5 + c2r[c1t][1], 0.f);
        acc[c1t][2] += aw*fmaxf(a2r[c1t][2]*x6 + c2r[c1t][2], 0.f);
        acc[c1t][3] += aw*fmaxf(a2r[c1t][3]*x7 + c2r[c1t][3], 0.f);
      }
    }
  }
  int row = w*16 + l16;
  #pragma unroll
  for (int ct = 0; ct < 4; ++ct)
    #pragma unroll
    for (int r = 0; r < 4; ++r)
      part[row*65 + ct*16 + quad*4 + r] = acc[ct][r];
  __syncthreads();
  if (t < 64){
    float a = 0.f;
    #pragma unroll 8
    for (int r = 0; r < 64; ++r) a += part[r*65 + t];
    s_att[t] = a * sinvS;
  }
  __syncthreads();
  if (t < 32){
    float z = M1b[t];
    #pragma unroll 8
    for (int c = 0; c < 64; ++c) z += s_att[c]*M1w[c*32 + t];
    ws[WS_Z + bn*32 + t] = z;
    int rep = bn & 63;
    atomicAdd(&ws[WS_ST3 + rep*64 + t], z);
    atomicAdd(&ws[WS_ST3 + rep*64 + 32 + t], z*z);
  }
}

// ---------------- K6: BN3 + head L2 -> logits ----------------
__global__ __launch_bounds__(256) void k6(const float* __restrict__ M1g,
    const float* __restrict__ M1be, const float* __restrict__ M2w,
    const float* __restrict__ M2b, const float* __restrict__ ws, float* __restrict__ out){
  int t = threadIdx.x; int s = blockIdx.x*256 + t;
  __shared__ float sa3[32], sc3[32];
  if (t < 32){
    float su = 0.f, q = 0.f;
    #pragma unroll 8
    for (int r = 0; r < 64; ++r){ su += ws[WS_ST3 + r*64 + t]; q += ws[WS_ST3 + r*64 + 32 + t]; }
    float mu = su/P3, var = q/P3 - mu*mu;
    float istd = rsqrtf(var + 1e-5f);
    float A3 = M1g[t]*istd;
    sa3[t] = A3; sc3[t] = M1be[t] - mu*A3;
  }
  __syncthreads();
  float a0 = M2b[0], a1 = M2b[1];
  #pragma unroll
  for (int j = 0; j < 32; ++j){
    float y = fmaxf(ws[WS_Z + s*32 + j]*sa3[j] + sc3[j], 0.f);
    a0 += y*M2w[j*2+0]; a1 += y*M2w[j*2+1];
  }
  out[s*2+0] = a0; out[s*2+1] = a1;
}

extern "C" void kernel_launch(void* const* d_in, const int* in_sizes, int n_in,
                              void* d_out, int out_size, void* d_ws, size_t ws_size,
                              hipStream_t stream){
  const float* wxyz = (const float*)d_in[0];
  const float* wpts = (const float*)d_in[1];
  const float* rf3  = (const float*)d_in[2];
  const float* rf3i = (const float*)d_in[3];
  const float* lz   = (const float*)d_in[4];
  const float* W1   = (const float*)d_in[5];
  const float* b1   = (const float*)d_in[6];
  const float* g1   = (const float*)d_in[7];
  const float* be1  = (const float*)d_in[8];
  const float* W2   = (const float*)d_in[9];
  const float* g2   = (const float*)d_in[11];
  const float* be2  = (const float*)d_in[12];
  const float* M1w  = (const float*)d_in[13];
  const float* M1b  = (const float*)d_in[14];
  const float* M1g  = (const float*)d_in[15];
  const float* M1be = (const float*)d_in[16];
  const float* M2w  = (const float*)d_in[17];
  const float* M2b  = (const float*)d_in[18];
  float* ws  = (float*)d_ws;
  float* out = (float*)d_out;
  // zero BN stat accumulators (ST1+ST2+ST3 contiguous: 28672 floats)
  hipMemsetAsync(ws + WS_ST1, 0, 28672*sizeof(float), stream);
  k1 <<<2048,128,0,stream>>>(wxyz, wpts, lz, rf3, rf3i, W1, ws);
  k2 <<<1024,256,0,stream>>>(ws);
  k2r<<<32,256,0,stream>>>(ws);
  k3 <<<2048,256,0,stream>>>(wxyz, W1, b1, ws);
  k3b<<<1041,128,0,stream>>>(W1, b1, g1, be1, W2, ws);
  k4 <<<2048,256,0,stream>>>(wxyz, ws);
  k5 <<<1024,256,0,stream>>>(g2, be2, M1w, M1b, ws);
  k6 <<<4,256,0,stream>>>(M1g, M1be, M2w, M2b, ws, out);
}

// Round 8
// 218.006 us; speedup vs baseline: 1.4233x; 1.0671x over previous
//
#include <hip/hip_runtime.h>
#include <hip/hip_bf16.h>

// Problem constants (B,N,H,W,C) = (2,512,16,32,64)
#define B_ 2
#define N_ 512
#define M_ 512
#define C_ 64
#define O1 128
#define O2 64
#define O3 32
#define PBIG 524288.0f   // B*N*M samples for BN1/BN2
#define P3   1024.0f     // B*N samples for BN3

typedef short s8v __attribute__((ext_vector_type(8)));   // 8 bf16 (4 VGPRs)
typedef float f4v __attribute__((ext_vector_type(4)));   // MFMA accumulator

// ---- workspace layout (float-element offsets) ----
#define WS_SRCN 0        //  [B][N][64]  (dead after k2 -> reused as WS_P0)
#define WS_DSTN 65536    //  [B][M][64]  (dead after k2 -> reused as WS_P0)
#define WS_P0   0        //  [B*N][128] BN1-folded per-(b,n) part (k3b)
#define WS_U    131072   //  [B][N][128] (dead after k3b -> reused as WS_Z)
#define WS_Z    131072   //  [B][N][32]  (k5 -> k6)
#define WS_V    262144   //  [B][M][128] (scaled by A1 in k3b, in place)
#define WS_DXY  393216   //  [B][M][2]
#define WS_COS  395264   //  [B][N][M]  -> ends 919552
#define WS_RMAX 919552   //  [B*N] INVERSE row max: 1/(max+1e-6)
#define WS_ROWS 920576   //  [3][1024] row sums: REN, RS1, RS2 (k3a)
#define WS_COLS 923648   //  [3][1024] col sums: CEN, CS1, CS2 (k2r)
#define WS_A1C  926720   //  [256] A1[128], C1[128] (k3s -> k3b,k4 via W9S/P0)
#define WS_SC2P 935936   //  [64][16] global scalar moment partials (k3a)
#define WS_ST2  936960   //  [64][128] BN2 partials -> 945152
#define WS_ST3  945152   //  [64][64]  BN3 partials -> 949248
#define WS_CMAX 949248   //  [B*M] INVERSE col max: 1/(max+1e-10)
#define WS_W2F  950272   //  bf16 [8192] fragment-packed W2 (k3b -> k4)
#define WS_W9S  954368   //  [3][128] A1-scaled W1 rank-1 columns
#define WS_X2   961536   //  bf16 fragment-major [B*N][4096] uint4 (64 KB per bn)

__device__ __forceinline__ unsigned short f2bf(float f){
  unsigned u = __float_as_uint(f);
  unsigned r = (u + 0x7fffu + ((u >> 16) & 1u)) >> 16;   // RNE
  return (unsigned short)r;
}
__device__ __forceinline__ float bf2f(unsigned short h){
  return __uint_as_float(((unsigned)h) << 16);
}
__device__ __forceinline__ unsigned pk2(float lo, float hi){
  return (unsigned)f2bf(lo) | ((unsigned)f2bf(hi) << 16);
}
// pack two f32 -> bf16x2 by truncation: one v_perm_b32 (used for MFMA inputs)
__device__ __forceinline__ unsigned pk_trunc(float lo, float hi){
  return __builtin_amdgcn_perm(__float_as_uint(hi), __float_as_uint(lo), 0x07060302u);
}
__device__ __forceinline__ f4v relu4(f4v z){
  z[0] = fmaxf(z[0], 0.f); z[1] = fmaxf(z[1], 0.f);
  z[2] = fmaxf(z[2], 0.f); z[3] = fmaxf(z[3], 0.f);
  return z;
}

// ---------------- K1: fused per-n (blk<1024) and per-m precompute ----------------
__global__ __launch_bounds__(128) void k1(const float* __restrict__ wxyz,
    const float* __restrict__ wpts, const float* __restrict__ lz,
    const float* __restrict__ rf3, const float* __restrict__ rf3i,
    const float* __restrict__ W1, float* __restrict__ ws){
  int t = threadIdx.x;
  if (blockIdx.x < 1024){
    int blk = blockIdx.x; int b = blk >> 9, n = blk & 511;
    int bn = b*N_ + n;
    __shared__ float wp[64]; __shared__ float sxyz[3]; __shared__ float slz; __shared__ float srn;
    if (t < 64) wp[t] = wpts[bn*64 + t];
    if (t >= 64 && t < 67) sxyz[t-64] = wxyz[bn*3 + (t-64)];
    if (t == 67) slz = lz[bn];
    __syncthreads();
    if (t < 64){
      float v = wp[t]*wp[t];
      v += __shfl_down(v,32); v += __shfl_down(v,16); v += __shfl_down(v,8);
      v += __shfl_down(v,4);  v += __shfl_down(v,2);  v += __shfl_down(v,1);
      if (t == 0) srn = 1.0f / fmaxf(sqrtf(v), 1e-12f);
    }
    __syncthreads();
    if (t < 64) ws[WS_SRCN + bn*64 + t] = wp[t]*srn;
    int o = t;
    float x = sxyz[0], y = sxyz[1], z = sxyz[2], l = slz;
    float acc = x*l*W1[0*O1+o] + y*l*W1[1*O1+o] + z*l*W1[2*O1+o]
              + wp[0]*W1[3*O1+o] + wp[1]*W1[4*O1+o]
              + x*W1[7*O1+o] + y*W1[8*O1+o];
    #pragma unroll 8
    for (int c = 0; c < 64; ++c) acc += wp[c]*W1[(10+c)*O1+o];
    ws[WS_U + bn*O1 + o] = acc;
  } else {
    int blk = blockIdx.x - 1024; int b = blk >> 9, m = blk & 511;
    int bm = b*M_ + m;
    __shared__ float rf[64]; __shared__ float sdx, sdy, srn2;
    if (t < 64) rf[t] = rf3[(b*64 + t)*512 + m];
    if (t == 64) sdx = rf3i[(b*3 + 0)*512 + m];
    if (t == 65) sdy = rf3i[(b*3 + 1)*512 + m];
    __syncthreads();
    if (t < 64){
      float v = rf[t]*rf[t];
      v += __shfl_down(v,32); v += __shfl_down(v,16); v += __shfl_down(v,8);
      v += __shfl_down(v,4);  v += __shfl_down(v,2);  v += __shfl_down(v,1);
      if (t == 0) srn2 = 1.0f / fmaxf(sqrtf(v), 1e-12f);
    }
    __syncthreads();
    if (t < 64) ws[WS_DSTN + bm*64 + t] = rf[t]*srn2;
    if (t == 0){ ws[WS_DXY + bm*2+0] = sdx; ws[WS_DXY + bm*2+1] = sdy; }
    int o = t;
    float acc = sdx*(W1[5*O1+o] - W1[7*O1+o]) + sdy*(W1[6*O1+o] - W1[8*O1+o]);
    #pragma unroll 8
    for (int c = 0; c < 64; ++c) acc += rf[c]*W1[(74+c)*O1+o];
    ws[WS_V + bm*O1 + o] = acc;
  }
}

// ---------------- K2: cos matrix + row-max (stored inverted), no atomics ----------------
__global__ __launch_bounds__(256) void k2(float* __restrict__ ws){
  int blk = blockIdx.x; int b = blk >> 9, n = blk & 511; int t = threadIdx.x;
  int bn = b*N_ + n;
  __shared__ __align__(16) float sn[64];
  __shared__ float dnt[64*65];   // +1 pad: conflict-free row reads
  __shared__ float part[4*64];
  if (t < 64) sn[t] = ws[WS_SRCN + bn*64 + t];
  float lmax = -3.4e38f;
  for (int chunk = 0; chunk < 8; ++chunk){
    __syncthreads();
    const float4* src = (const float4*)(ws + WS_DSTN + (size_t)(b*M_ + chunk*64)*64);
    #pragma unroll
    for (int i = 0; i < 4; ++i){
      float4 v = src[t + i*256];
      int base = (t + i*256)*4; int mm = base >> 6, c = base & 63;
      float* dp = &dnt[mm*65 + c];
      dp[0]=v.x; dp[1]=v.y; dp[2]=v.z; dp[3]=v.w;
    }
    __syncthreads();
    {
      int mm = t & 63, cg = t >> 6;
      const float* dr = &dnt[mm*65 + cg*16];
      const float* sr = &sn[cg*16];
      float p = 0.f;
      #pragma unroll
      for (int k = 0; k < 16; ++k) p += sr[k]*dr[k];
      part[cg*64 + mm] = p;
    }
    __syncthreads();
    if (t < 64){
      float d = part[t] + part[64+t] + part[128+t] + part[192+t];
      ws[WS_COS + bn*M_ + chunk*64 + t] = d;
      lmax = fmaxf(lmax, d);
    }
  }
  if (t < 64){
    lmax = fmaxf(lmax, __shfl_xor(lmax,32)); lmax = fmaxf(lmax, __shfl_xor(lmax,16));
    lmax = fmaxf(lmax, __shfl_xor(lmax,8));  lmax = fmaxf(lmax, __shfl_xor(lmax,4));
    lmax = fmaxf(lmax, __shfl_xor(lmax,2));  lmax = fmaxf(lmax, __shfl_xor(lmax,1));
    if (t == 0) ws[WS_RMAX + bn] = 1.0f / (lmax + 1e-6f);
  }
}

// ---------------- K2r: per-column max (inverted) + col sums CEN/CS1/CS2 ----------------
__global__ __launch_bounds__(256) void k2r(const float* __restrict__ wxyz, float* __restrict__ ws){
  int blk = blockIdx.x;            // 64 blocks: b = blk>>5, 16-col group = blk&31
  int b = blk >> 5; int c0 = (blk & 31)*16;
  int t = threadIdx.x;
  int cl = t & 15, seg = t >> 4;   // 16 segs x 32 rows
  int col = c0 + cl;
  int bm = b*M_ + col;
  float dx = ws[WS_DXY + bm*2+0], dy = ws[WS_DXY + bm*2+1];
  float mx = -3.4e38f, se = 0.f, sc = 0.f, s1c = 0.f;
  for (int i = 0; i < 32; ++i){
    int bn = b*N_ + seg*32 + i;
    float cv = ws[WS_COS + (size_t)bn*M_ + col];
    float ri = ws[WS_RMAX + bn];
    float sx = wxyz[bn*3+0], sy = wxyz[bn*3+1];
    float ex = sx-dx, ey = sy-dy;
    se += sqrtf(ex*ex + ey*ey);
    mx = fmaxf(mx, cv);
    sc += cv;
    s1c += cv*ri;
  }
  __shared__ float r0[256], r1[256], r2[256], r3[256];
  r0[t]=mx; r1[t]=se; r2[t]=s1c; r3[t]=sc;
  __syncthreads();
  for (int s = 8; s > 0; s >>= 1){
    if (seg < s){
      int o2 = t + s*16;
      r0[t] = fmaxf(r0[t], r0[o2]); r1[t] += r1[o2]; r2[t] += r2[o2]; r3[t] += r3[o2];
    }
    __syncthreads();
  }
  if (t < 16){
    int bmw = b*M_ + c0 + t;
    float ci = 1.0f/(r0[t] + 1e-10f);
    ws[WS_CMAX + bmw] = ci;
    ws[WS_COLS + bmw] = r1[t];             // CEN
    ws[WS_COLS + 1024 + bmw] = r2[t];      // CS1
    ws[WS_COLS + 2048 + bmw] = r3[t]*ci;   // CS2
  }
}

// ---------------- K3a: row sums + 9 global scalar moments from COS pass ----------------
__global__ __launch_bounds__(256) void k3a(const float* __restrict__ wxyz, float* __restrict__ ws){
  int bn = blockIdx.x; int b = bn >> 9; int t = threadIdx.x;
  float ri = ws[WS_RMAX + bn];
  float sx = wxyz[bn*3+0], sy = wxyz[bn*3+1];
  float q[9];
  #pragma unroll
  for (int j = 0; j < 9; ++j) q[j] = 0.f;
  #pragma unroll
  for (int k = 0; k < 2; ++k){
    int m = t + k*256;
    float2 d = *(const float2*)(ws + WS_DXY + (size_t)(b*M_+m)*2);
    float ex = sx-d.x, ey = sy-d.y;
    float en = sqrtf(ex*ex + ey*ey);
    float cv = ws[WS_COS + (size_t)bn*M_ + m];
    float ci = ws[WS_CMAX + b*M_ + m];
    float s2 = cv*ci;
    q[0]+=en; q[1]+=cv; q[2]+=s2; q[3]+=en*en; q[4]+=cv*cv; q[5]+=s2*s2;
    q[6]+=en*cv; q[7]+=en*s2; q[8]+=cv*cv*ci;
  }
  #pragma unroll
  for (int j = 0; j < 9; ++j){
    float v = q[j];
    v += __shfl_xor(v,1); v += __shfl_xor(v,2); v += __shfl_xor(v,4);
    v += __shfl_xor(v,8); v += __shfl_xor(v,16); v += __shfl_xor(v,32);
    q[j] = v;
  }
  __shared__ float wr[9][4];
  int w = t >> 6;
  if ((t & 63) == 0){
    #pragma unroll
    for (int j = 0; j < 9; ++j) wr[j][w] = q[j];
  }
  __syncthreads();
  if (t < 9){
    float Q = wr[t][0] + wr[t][1] + wr[t][2] + wr[t][3];
    float f = (t==1 || t==6 || t==8) ? ri : ((t==4) ? ri*ri : 1.0f);
    float s = f*Q;
    if (t < 3) ws[WS_ROWS + t*1024 + bn] = s;   // REN, RS1(=ri*rcos), RS2
    atomicAdd(&ws[WS_SC2P + (bn & 63)*16 + t], s);
  }
}

// ---------------- K3s: closed-form BN1 stats per channel o -> A1/C1 ----------------
__global__ __launch_bounds__(256) void k3s(const float* __restrict__ W1,
    const float* __restrict__ b1, const float* __restrict__ g1,
    const float* __restrict__ be1, float* __restrict__ ws){
  int o = blockIdx.x; int t = threadIdx.x;
  __shared__ float scal[9];
  __shared__ float wr[12][4];
  if (t < 9){
    float s = 0.f;
    #pragma unroll 8
    for (int r = 0; r < 64; ++r) s += ws[WS_SC2P + r*16 + t];
    scal[t] = s;
  }
  float b1o = b1[o];
  float a[12];
  #pragma unroll
  for (int j = 0; j < 12; ++j) a[j] = 0.f;
  #pragma unroll
  for (int k = 0; k < 4; ++k){
    int i = t + k*256;
    float u = ws[WS_U + (size_t)i*O1 + o] + b1o;
    float v = ws[WS_V + (size_t)i*O1 + o];
    float ren = ws[WS_ROWS + i], rs1 = ws[WS_ROWS + 1024 + i], rs2 = ws[WS_ROWS + 2048 + i];
    float cen = ws[WS_COLS + i], cs1 = ws[WS_COLS + 1024 + i], cs2 = ws[WS_COLS + 2048 + i];
    a[0]+=u; a[1]+=u*u; a[2]+=u*ren; a[3]+=u*rs1; a[4]+=u*rs2;
    a[5]+=v; a[6]+=v*v; a[7]+=v*cen; a[8]+=v*cs1; a[9]+=v*cs2;
    if (k < 2){ a[10]+=u; a[11]+=v; }   // b=0 partial sums
  }
  #pragma unroll
  for (int j = 0; j < 12; ++j){
    float v = a[j];
    v += __shfl_xor(v,1); v += __shfl_xor(v,2); v += __shfl_xor(v,4);
    v += __shfl_xor(v,8); v += __shfl_xor(v,16); v += __shfl_xor(v,32);
    a[j] = v;
  }
  int w = t >> 6;
  if ((t & 63) == 0){
    #pragma unroll
    for (int j = 0; j < 12; ++j) wr[j][w] = a[j];
  }
  __syncthreads();
  if (t == 0){
    float A[12];
    #pragma unroll
    for (int j = 0; j < 12; ++j) A[j] = wr[j][0] + wr[j][1] + wr[j][2] + wr[j][3];
    float w9 = W1[9*O1+o], wa = W1[138*O1+o], wb = W1[139*O1+o];
    float S1 = 512.f*(A[0] + A[5]) + w9*scal[0] + wa*scal[1] + wb*scal[2];
    float Q1 = 512.f*(A[1] + A[6])
      + 2.f*(A[10]*A[11] + (A[0]-A[10])*(A[5]-A[11]))
      + w9*w9*scal[3] + wa*wa*scal[4] + wb*wb*scal[5]
      + 2.f*(w9*wa*scal[6] + w9*wb*scal[7] + wa*wb*scal[8])
      + 2.f*(w9*A[2] + wa*A[3] + wb*A[4])
      + 2.f*(w9*A[7] + wa*A[8] + wb*A[9]);
    float mu = S1/PBIG, var = Q1/PBIG - mu*mu;
    float istd = rsqrtf(var + 1e-5f);
    float A1v = g1[o]*istd;
    ws[WS_A1C + o] = A1v;
    ws[WS_A1C + 128 + o] = be1[o] - mu*A1v;
  }
}

// ---------------- K3b: P0; scale V by A1; pack W2 frags (A1/C1 precomputed) ----------------
__global__ __launch_bounds__(128) void k3b(const float* __restrict__ W1,
    const float* __restrict__ b1, const float* __restrict__ W2, float* __restrict__ ws){
  int blk = blockIdx.x; int t = threadIdx.x; int o = t;
  float A1 = ws[WS_A1C + o], C1 = ws[WS_A1C + 128 + o];
  if (blk < 1024){                       // P0[bn][o]
    ws[WS_P0 + blk*O1 + o] = (ws[WS_U + blk*O1 + o] + b1[o])*A1 + C1;
  } else if (blk < 1088){                // V *= A1, 16 rows per block
    int r0 = (blk - 1024)*16;
    #pragma unroll
    for (int r = 0; r < 16; ++r)
      ws[WS_V + (size_t)(r0 + r)*O1 + o] *= A1;
  } else {                               // scaled rank-1 cols + W2 fragment pack
    ws[WS_W9S + o]       = W1[9*O1+o]*A1;
    ws[WS_W9S + 128 + o] = W1[138*O1+o]*A1;
    ws[WS_W9S + 256 + o] = W1[139*O1+o]*A1;
    unsigned short* wf = (unsigned short*)(ws + WS_W2F);
    for (int i = t; i < 8192; i += 128){
      int j = i & 7, ll = (i >> 3) & 63, ct = (i >> 9) & 3, k0q = i >> 11;
      int oo = k0q*32 + (ll >> 4)*8 + j, c = ct*16 + (ll & 15);
      wf[i] = f2bf(W2[oo*O2 + c]);
    }
  }
}

// ---------------- K4: 1 m-chunk per block (grid 4096); uint4 x2 store; no spill ----
// block=256, min 4 waves/EU: VGPR ~60, NO scratch spill. (256,8) forced VGPR=32
// and spilled: WRITE_SIZE 280MB, dur 125us. Keep 4.
__global__ __launch_bounds__(256, 4) void k4(const float* __restrict__ wxyz,
    float* __restrict__ ws){
  int blk = blockIdx.x; int bn = blk >> 2, mc = blk & 3;
  int b = bn >> 9; int t = threadIdx.x;
  __shared__ __align__(16) unsigned short wBf[8192];        // 16 KB fragment-packed W2
  __shared__ __align__(16) float p0s[128], w9s[128], was[128], wbs[128];
  __shared__ float ls[64], lq[64];
  {   // stage W2 fragments: lane-consecutive 16B (conflict-free)
    const s8v* g = (const s8v*)(ws + WS_W2F);
    s8v* l = (s8v*)wBf;
    #pragma unroll
    for (int c2 = 0; c2 < 4; ++c2) l[c2*256 + t] = g[c2*256 + t];
  }
  if (t < 64){ ls[t] = 0.f; lq[t] = 0.f; }
  if (t < 128){
    p0s[t] = ws[WS_P0 + bn*O1 + t];
    w9s[t] = ws[WS_W9S + t];
    was[t] = ws[WS_W9S + 128 + t];
    wbs[t] = ws[WS_W9S + 256 + t];
  }
  __syncthreads();
  // barrier-free from here until the final stat reduce
  int ll = t & 63, w = t >> 6, l16 = ll & 15, quad = ll >> 4;
  float sx = wxyz[bn*3+0], sy = wxyz[bn*3+1];
  float ri = ws[WS_RMAX + bn];
  uint4* xf4 = (uint4*)(ws + WS_X2) + (size_t)bn*4096;
  union U8 { s8v v; unsigned u[4]; };
  int mA = mc*128 + w*32 + l16, mB = mA + 16;
  float2 dA = *(const float2*)(ws + WS_DXY + (size_t)(b*M_+mA)*2);
  float2 dB = *(const float2*)(ws + WS_DXY + (size_t)(b*M_+mB)*2);
  float cvA = ws[WS_COS + (size_t)bn*M_ + mA], cvB = ws[WS_COS + (size_t)bn*M_ + mB];
  float ciA = ws[WS_CMAX + b*M_ + mA],         ciB = ws[WS_CMAX + b*M_ + mB];
  float exA = sx-dA.x, eyA = sy-dA.y; float en0 = sqrtf(exA*exA + eyA*eyA);
  float exB = sx-dB.x, eyB = sy-dB.y; float en1 = sqrtf(exB*exB + eyB*eyB);
  float s10 = cvA*ri, s20 = cvA*ciA;
  float s11 = cvB*ri, s21 = cvB*ciB;
  const float* vpA = ws + WS_V + (size_t)(b*M_+mA)*O1;
  const float* vpB = ws + WS_V + (size_t)(b*M_+mB)*O1;
  f4v acc[2][4];
  #pragma unroll
  for (int i = 0; i < 2; ++i)
    #pragma unroll
    for (int j = 0; j < 4; ++j) acc[i][j] = (f4v){0.f,0.f,0.f,0.f};
  #pragma unroll
  for (int k0q = 0; k0q < 4; ++k0q){
    int ko = k0q*32 + quad*8;
    f4v p0a = *(const f4v*)&p0s[ko], p0b = *(const f4v*)&p0s[ko+4];
    f4v w9a = *(const f4v*)&w9s[ko], w9b = *(const f4v*)&w9s[ko+4];
    f4v waa = *(const f4v*)&was[ko], wab = *(const f4v*)&was[ko+4];
    f4v wba = *(const f4v*)&wbs[ko], wbb = *(const f4v*)&wbs[ko+4];
    f4v vA0 = *(const f4v*)(vpA + ko), vA1 = *(const f4v*)(vpA + ko + 4);
    f4v vB0 = *(const f4v*)(vpB + ko), vB1 = *(const f4v*)(vpB + ko + 4);
    f4v zaA = relu4(p0a + vA0 + en0*w9a + s10*waa + s20*wba);
    f4v zbA = relu4(p0b + vA1 + en0*w9b + s10*wab + s20*wbb);
    f4v zaB = relu4(p0a + vB0 + en1*w9a + s11*waa + s21*wba);
    f4v zbB = relu4(p0b + vB1 + en1*w9b + s11*wab + s21*wbb);
    U8 uA, uB;
    uA.u[0] = pk_trunc(zaA[0], zaA[1]); uA.u[1] = pk_trunc(zaA[2], zaA[3]);
    uA.u[2] = pk_trunc(zbA[0], zbA[1]); uA.u[3] = pk_trunc(zbA[2], zbA[3]);
    uB.u[0] = pk_trunc(zaB[0], zaB[1]); uB.u[1] = pk_trunc(zaB[2], zaB[3]);
    uB.u[2] = pk_trunc(zbB[0], zbB[1]); uB.u[3] = pk_trunc(zbB[2], zbB[3]);
    #pragma unroll
    for (int ct = 0; ct < 4; ++ct){
      s8v bb = *(const s8v*)&wBf[((k0q*4 + ct)*64 + ll)*8];
      acc[0][ct] = __builtin_amdgcn_mfma_f32_16x16x32_bf16(bb, uA.v, acc[0][ct], 0,0,0);
      acc[1][ct] = __builtin_amdgcn_mfma_f32_16x16x32_bf16(bb, uB.v, acc[1][ct], 0,0,0);
    }
  }
  // fragment-major store, 16 B/lane: wave writes 1024 B contiguous per inst
  #pragma unroll
  for (int mt = 0; mt < 2; ++mt){
    uint4 u0, u1;
    u0.x = pk2(acc[mt][0][0], acc[mt][0][1]); u0.y = pk2(acc[mt][0][2], acc[mt][0][3]);
    u0.z = pk2(acc[mt][1][0], acc[mt][1][1]); u0.w = pk2(acc[mt][1][2], acc[mt][1][3]);
    u1.x = pk2(acc[mt][2][0], acc[mt][2][1]); u1.y = pk2(acc[mt][2][2], acc[mt][2][3]);
    u1.z = pk2(acc[mt][3][0], acc[mt][3][1]); u1.w = pk2(acc[mt][3][2], acc[mt][3][3]);
    xf4[((((mc*4 + w)*2 + mt)*2 + 0)*64) + ll] = u0;
    xf4[((((mc*4 + w)*2 + mt)*2 + 1)*64) + ll] = u1;
  }
  // BN2 stat reduce: over the 16 lanes of each quad-group, then LDS
  #pragma unroll
  for (int ct = 0; ct < 4; ++ct){
    #pragma unroll
    for (int r = 0; r < 4; ++r){
      float a0 = acc[0][ct][r], a1 = acc[1][ct][r];
      float s = a0 + a1;
      float q = a0*a0 + a1*a1;
      s += __shfl_xor(s,1); s += __shfl_xor(s,2); s += __shfl_xor(s,4); s += __shfl_xor(s,8);
      q += __shfl_xor(q,1); q += __shfl_xor(q,2); q += __shfl_xor(q,4); q += __shfl_xor(q,8);
      if (l16 == 0){
        atomicAdd(&ls[ct*16 + quad*4 + r], s);
        atomicAdd(&lq[ct*16 + quad*4 + r], q);
      }
    }
  }
  __syncthreads();
  int rep = blk & 63;
  if (t < 64) atomicAdd(&ws[WS_ST2 + rep*128 + t], ls[t]);
  else if (t < 128) atomicAdd(&ws[WS_ST2 + rep*128 + t], lq[t-64]);
}

// ---------------- K5: BN2 + softmax pool from uint4 fragment-major x2 ----------------
__global__ __launch_bounds__(256) void k5(const float* __restrict__ g2,
    const float* __restrict__ be2, const float* __restrict__ M1w,
    const float* __restrict__ M1b, float* __restrict__ ws){
  int bn = blockIdx.x; int t = threadIdx.x;
  __shared__ float sa2[64], sc2[64];
  __shared__ float s_mx[512];
  __shared__ float s_aw[512];
  __shared__ float red[256];
  __shared__ float part[64*65];
  __shared__ float s_att[64];
  __shared__ float sgmax, sinvS;
  if (t < 64){
    float s = 0.f, q = 0.f;
    #pragma unroll 8
    for (int r = 0; r < 64; ++r){ s += ws[WS_ST2 + r*128 + t]; q += ws[WS_ST2 + r*128 + 64 + t]; }
    float mu = s/PBIG, var = q/PBIG - mu*mu;
    float istd = rsqrtf(var + 1e-5f);
    float A2 = g2[t]*istd;
    sa2[t] = A2; sc2[t] = be2[t] - mu*A2;
  }
  __syncthreads();
  int ll = t & 63, w = t >> 6, l16 = ll & 15, quad = ll >> 4;
  const uint4* xf4 = (const uint4*)(ws + WS_X2) + (size_t)bn*4096;
  uint4 xv[4][2][2];   // [mc][mt][cp]
  #pragma unroll
  for (int mc = 0; mc < 4; ++mc)
    #pragma unroll
    for (int mt = 0; mt < 2; ++mt)
      #pragma unroll
      for (int cp = 0; cp < 2; ++cp)
        xv[mc][mt][cp] = xf4[((((mc*4 + w)*2 + mt)*2 + cp)*64) + ll];
  float a2r[4][4], c2r[4][4];
  #pragma unroll
  for (int ct = 0; ct < 4; ++ct)
    #pragma unroll
    for (int r = 0; r < 4; ++r){
      int c = ct*16 + quad*4 + r;
      a2r[ct][r] = sa2[c]; c2r[ct][r] = sc2[c];
    }
  // Pass A: per-m max over channels; 2 shuffles (across quads)
  #pragma unroll
  for (int mc = 0; mc < 4; ++mc){
    #pragma unroll
    for (int mt = 0; mt < 2; ++mt){
      float mx = 0.f;   // relu >= 0
      #pragma unroll
      for (int cp = 0; cp < 2; ++cp){
        uint4 uv = xv[mc][mt][cp];
        int c0t = 2*cp, c1t = 2*cp + 1;
        float x0 = bf2f((unsigned short)(uv.x & 0xffffu));
        float x1 = bf2f((unsigned short)(uv.x >> 16));
        float x2 = bf2f((unsigned short)(uv.y & 0xffffu));
        float x3 = bf2f((unsigned short)(uv.y >> 16));
        float x4 = bf2f((unsigned short)(uv.z & 0xffffu));
        float x5 = bf2f((unsigned short)(uv.z >> 16));
        float x6 = bf2f((unsigned short)(uv.w & 0xffffu));
        float x7 = bf2f((unsigned short)(uv.w >> 16));
        mx = fmaxf(mx, a2r[c0t][0]*x0 + c2r[c0t][0]);
        mx = fmaxf(mx, a2r[c0t][1]*x1 + c2r[c0t][1]);
        mx = fmaxf(mx, a2r[c0t][2]*x2 + c2r[c0t][2]);
        mx = fmaxf(mx, a2r[c0t][3]*x3 + c2r[c0t][3]);
        mx = fmaxf(mx, a2r[c1t][0]*x4 + c2r[c1t][0]);
        mx = fmaxf(mx, a2r[c1t][1]*x5 + c2r[c1t][1]);
        mx = fmaxf(mx, a2r[c1t][2]*x6 + c2r[c1t][2]);
        mx = fmaxf(mx, a2r[c1t][3]*x7 + c2r[c1t][3]);
      }
      mx = fmaxf(mx, __shfl_xor(mx,16));
      mx = fmaxf(mx, __shfl_xor(mx,32));
      if (quad == 0) s_mx[mc*128 + w*32 + mt*16 + l16] = mx;
    }
  }
  __syncthreads();
  red[t] = fmaxf(s_mx[t], s_mx[t+256]);
  __syncthreads();
  for (int s = 128; s > 0; s >>= 1){ if (t < s) red[t] = fmaxf(red[t], red[t+s]); __syncthreads(); }
  if (t == 0) sgmax = red[0];
  __syncthreads();
  float e0 = expf(s_mx[t] - sgmax), e1 = expf(s_mx[t+256] - sgmax);
  s_aw[t] = e0; s_aw[t+256] = e1;
  red[t] = e0 + e1;
  __syncthreads();
  for (int s = 128; s > 0; s >>= 1){ if (t < s) red[t] += red[t+s]; __syncthreads(); }
  if (t == 0) sinvS = 1.0f / red[0];
  __syncthreads();
  // Pass C: weighted sum (y recomputed from registers)
  float acc[4][4];
  #pragma unroll
  for (int ct = 0; ct < 4; ++ct)
    #pragma unroll
    for (int r = 0; r < 4; ++r) acc[ct][r] = 0.f;
  #pragma unroll
  for (int mc = 0; mc < 4; ++mc){
    #pragma unroll
    for (int mt = 0; mt < 2; ++mt){
      float aw = s_aw[mc*128 + w*32 + mt*16 + l16];
      #pragma unroll
      for (int cp = 0; cp < 2; ++cp){
        uint4 uv = xv[mc][mt][cp];
        int c0t = 2*cp, c1t = 2*cp + 1;
        float x0 = bf2f((unsigned short)(uv.x & 0xffffu));
        float x1 = bf2f((unsigned short)(uv.x >> 16));
        float x2 = bf2f((unsigned short)(uv.y & 0xffffu));
        float x3 = bf2f((unsigned short)(uv.y >> 16));
        float x4 = bf2f((unsigned short)(uv.z & 0xffffu));
        float x5 = bf2f((unsigned short)(uv.z >> 16));
        float x6 = bf2f((unsigned short)(uv.w & 0xffffu));
        float x7 = bf2f((unsigned short)(uv.w >> 16));
        acc[c0t][0] += aw*fmaxf(a2r[c0t][0]*x0 + c2r[c0t][0], 0.f);
        acc[c0t][1] += aw*fmaxf(a2r[c0t][1]*x1 + c2r[c0t][1], 0.f);
        acc[c0t][2] += aw*fmaxf(a2r[c0t][2]*x2 + c2r[c0t][2], 0.f);
        acc[c0t][3] += aw*fmaxf(a2r[c0t][3]*x3 + c2r[c0t][3], 0.f);
        acc[c1t][0] += aw*fmaxf(a2r[c1t][0]*x4 + c2r[c1t][0], 0.f);
        acc[c1t][1] += aw*fmaxf(a2r[c1t][1]*x5 + c2r[c1t][1], 0.f);
        acc[c1t][2] += aw*fmaxf(a2r[c1t][2]*x6 + c2r[c1t][2], 0.f);
        acc[c1t][3] += aw*fmaxf(a2r[c1t][3]*x7 + c2r[c1t][3], 0.f);
      }
    }
  }
  int row = w*16 + l16;
  #pragma unroll
  for (int ct = 0; ct < 4; ++ct)
    #pragma unroll
    for (int r = 0; r < 4; ++r)
      part[row*65 + ct*16 + quad*4 + r] = acc[ct][r];
  __syncthreads();
  if (t < 64){
    float a = 0.f;
    #pragma unroll 8
    for (int r = 0; r < 64; ++r) a += part[r*65 + t];
    s_att[t] = a * sinvS;
  }
  __syncthreads();
  if (t < 32){
    float z = M1b[t];
    #pragma unroll 8
    for (int c = 0; c < 64; ++c) z += s_att[c]*M1w[c*32 + t];
    ws[WS_Z + bn*32 + t] = z;
    int rep = bn & 63;
    atomicAdd(&ws[WS_ST3 + rep*64 + t], z);
    atomicAdd(&ws[WS_ST3 + rep*64 + 32 + t], z*z);
  }
}

// ---------------- K6: BN3 + head L2 -> logits ----------------
__global__ __launch_bounds__(256) void k6(const float* __restrict__ M1g,
    const float* __restrict__ M1be, const float* __restrict__ M2w,
    const float* __restrict__ M2b, const float* __restrict__ ws, float* __restrict__ out){
  int t = threadIdx.x; int s = blockIdx.x*256 + t;
  __shared__ float sa3[32], sc3[32];
  if (t < 32){
    float su = 0.f, q = 0.f;
    #pragma unroll 8
    for (int r = 0; r < 64; ++r){ su += ws[WS_ST3 + r*64 + t]; q += ws[WS_ST3 + r*64 + 32 + t]; }
    float mu = su/P3, var = q/P3 - mu*mu;
    float istd = rsqrtf(var + 1e-5f);
    float A3 = M1g[t]*istd;
    sa3[t] = A3; sc3[t] = M1be[t] - mu*A3;
  }
  __syncthreads();
  float a0 = M2b[0], a1 = M2b[1];
  #pragma unroll
  for (int j = 0; j < 32; ++j){
    float y = fmaxf(ws[WS_Z + s*32 + j]*sa3[j] + sc3[j], 0.f);
    a0 += y*M2w[j*2+0]; a1 += y*M2w[j*2+1];
  }
  out[s*2+0] = a0; out[s*2+1] = a1;
}

extern "C" void kernel_launch(void* const* d_in, const int* in_sizes, int n_in,
                              void* d_out, int out_size, void* d_ws, size_t ws_size,
                              hipStream_t stream){
  const float* wxyz = (const float*)d_in[0];
  const float* wpts = (const float*)d_in[1];
  const float* rf3  = (const float*)d_in[2];
  const float* rf3i = (const float*)d_in[3];
  const float* lz   = (const float*)d_in[4];
  const float* W1   = (const float*)d_in[5];
  const float* b1   = (const float*)d_in[6];
  const float* g1   = (const float*)d_in[7];
  const float* be1  = (const float*)d_in[8];
  const float* W2   = (const float*)d_in[9];
  const float* g2   = (const float*)d_in[11];
  const float* be2  = (const float*)d_in[12];
  const float* M1w  = (const float*)d_in[13];
  const float* M1b  = (const float*)d_in[14];
  const float* M1g  = (const float*)d_in[15];
  const float* M1be = (const float*)d_in[16];
  const float* M2w  = (const float*)d_in[17];
  const float* M2b  = (const float*)d_in[18];
  float* ws  = (float*)d_ws;
  float* out = (float*)d_out;
  // zero SC2P + ST2 + ST3 (contiguous 935936..949248 = 13312 floats)
  hipMemsetAsync(ws + WS_SC2P, 0, 13312*sizeof(float), stream);
  k1 <<<2048,128,0,stream>>>(wxyz, wpts, lz, rf3, rf3i, W1, ws);
  k2 <<<1024,256,0,stream>>>(ws);
  k2r<<<64,256,0,stream>>>(wxyz, ws);
  k3a<<<1024,256,0,stream>>>(wxyz, ws);
  k3s<<<128,256,0,stream>>>(W1, b1, g1, be1, ws);
  k3b<<<1089,128,0,stream>>>(W1, b1, W2, ws);
  k4 <<<4096,256,0,stream>>>(wxyz, ws);
  k5 <<<1024,256,0,stream>>>(g2, be2, M1w, M1b, ws);
  k6 <<<4,256,0,stream>>>(M1g, M1be, M2w, M2b, ws, out);
}

// Round 9
// 211.253 us; speedup vs baseline: 1.4688x; 1.0320x over previous
//
#include <hip/hip_runtime.h>
#include <hip/hip_bf16.h>

// Problem constants (B,N,H,W,C) = (2,512,16,32,64)
#define B_ 2
#define N_ 512
#define M_ 512
#define C_ 64
#define O1 128
#define O2 64
#define O3 32
#define PBIG 524288.0f   // B*N*M samples for BN1/BN2
#define P3   1024.0f     // B*N samples for BN3

typedef short s8v __attribute__((ext_vector_type(8)));   // 8 bf16 (4 VGPRs)
typedef float f4v __attribute__((ext_vector_type(4)));   // MFMA accumulator

// ---- workspace layout (float-element offsets) ----
#define WS_SRCN 0        //  [B][N][64]  (dead after k2 -> reused as WS_P0)
#define WS_DSTN 65536    //  [B][M][64]  (dead after k2 -> reused as WS_P0)
#define WS_P0   0        //  [B*N][128] BN1-folded per-(b,n) part (k3s)
#define WS_U    131072   //  [B][N][128] (dead after k3s -> reused as WS_Z)
#define WS_Z    131072   //  [B][N][32]  (k5 -> k6)
#define WS_V    262144   //  [B][M][128] (unscaled; k3s consumes)
#define WS_DXY  393216   //  [B][M][2]
#define WS_COS  395264   //  [B][N][M]  -> ends 919552
#define WS_RMAX 919552   //  [B*N] INVERSE row max: 1/(max+1e-6)
#define WS_ROWS 920576   //  [3][1024] row sums: REN, RS1, RS2 (k3a)
#define WS_COLS 923648   //  [3][1024] col sums: CEN, CS1, CS2 (k2r)
#define WS_SC2P 935936   //  [64][16] global scalar moment partials (k3a)
#define WS_ST2  936960   //  [64][128] BN2 partials -> 945152
#define WS_ST3  945152   //  [64][64]  BN3 partials -> 949248
#define WS_CMAX 949248   //  [B*M] INVERSE col max: 1/(max+1e-10)
#define WS_W2F  950272   //  bf16 [8192] fragment-packed W2 (k1 -> k4)
#define WS_W9S  954368   //  [3][128] A1-scaled W1 rank-1 columns (k3s)
#define WS_X2   961536   //  bf16 fragment-major [B*N][4096] uint4 (64 KB per bn)
#define WS_VF   17738752 //  [2][4][4][4][2][64][8] A1-scaled V in k4 fragment order (512 KB)

__device__ __forceinline__ unsigned short f2bf(float f){
  unsigned u = __float_as_uint(f);
  unsigned r = (u + 0x7fffu + ((u >> 16) & 1u)) >> 16;   // RNE
  return (unsigned short)r;
}
__device__ __forceinline__ float bf2f(unsigned short h){
  return __uint_as_float(((unsigned)h) << 16);
}
__device__ __forceinline__ unsigned pk2(float lo, float hi){
  return (unsigned)f2bf(lo) | ((unsigned)f2bf(hi) << 16);
}
// pack two f32 -> bf16x2 by truncation: one v_perm_b32 (used for MFMA inputs)
__device__ __forceinline__ unsigned pk_trunc(float lo, float hi){
  return __builtin_amdgcn_perm(__float_as_uint(hi), __float_as_uint(lo), 0x07060302u);
}
__device__ __forceinline__ f4v relu4(f4v z){
  z[0] = fmaxf(z[0], 0.f); z[1] = fmaxf(z[1], 0.f);
  z[2] = fmaxf(z[2], 0.f); z[3] = fmaxf(z[3], 0.f);
  return z;
}

// ---------------- K1: per-n (blk<1024), per-m (1024..2047), W2 pack (2048) ----------------
__global__ __launch_bounds__(128) void k1(const float* __restrict__ wxyz,
    const float* __restrict__ wpts, const float* __restrict__ lz,
    const float* __restrict__ rf3, const float* __restrict__ rf3i,
    const float* __restrict__ W1, const float* __restrict__ W2, float* __restrict__ ws){
  int t = threadIdx.x;
  if (blockIdx.x < 1024){
    int blk = blockIdx.x; int b = blk >> 9, n = blk & 511;
    int bn = b*N_ + n;
    __shared__ float wp[64]; __shared__ float sxyz[3]; __shared__ float slz; __shared__ float srn;
    if (t < 64) wp[t] = wpts[bn*64 + t];
    if (t >= 64 && t < 67) sxyz[t-64] = wxyz[bn*3 + (t-64)];
    if (t == 67) slz = lz[bn];
    __syncthreads();
    if (t < 64){
      float v = wp[t]*wp[t];
      v += __shfl_down(v,32); v += __shfl_down(v,16); v += __shfl_down(v,8);
      v += __shfl_down(v,4);  v += __shfl_down(v,2);  v += __shfl_down(v,1);
      if (t == 0) srn = 1.0f / fmaxf(sqrtf(v), 1e-12f);
    }
    __syncthreads();
    if (t < 64) ws[WS_SRCN + bn*64 + t] = wp[t]*srn;
    int o = t;
    float x = sxyz[0], y = sxyz[1], z = sxyz[2], l = slz;
    float acc = x*l*W1[0*O1+o] + y*l*W1[1*O1+o] + z*l*W1[2*O1+o]
              + wp[0]*W1[3*O1+o] + wp[1]*W1[4*O1+o]
              + x*W1[7*O1+o] + y*W1[8*O1+o];
    #pragma unroll 8
    for (int c = 0; c < 64; ++c) acc += wp[c]*W1[(10+c)*O1+o];
    ws[WS_U + bn*O1 + o] = acc;
  } else if (blockIdx.x < 2048){
    int blk = blockIdx.x - 1024; int b = blk >> 9, m = blk & 511;
    int bm = b*M_ + m;
    __shared__ float rf[64]; __shared__ float sdx, sdy, srn2;
    if (t < 64) rf[t] = rf3[(b*64 + t)*512 + m];
    if (t == 64) sdx = rf3i[(b*3 + 0)*512 + m];
    if (t == 65) sdy = rf3i[(b*3 + 1)*512 + m];
    __syncthreads();
    if (t < 64){
      float v = rf[t]*rf[t];
      v += __shfl_down(v,32); v += __shfl_down(v,16); v += __shfl_down(v,8);
      v += __shfl_down(v,4);  v += __shfl_down(v,2);  v += __shfl_down(v,1);
      if (t == 0) srn2 = 1.0f / fmaxf(sqrtf(v), 1e-12f);
    }
    __syncthreads();
    if (t < 64) ws[WS_DSTN + bm*64 + t] = rf[t]*srn2;
    if (t == 0){ ws[WS_DXY + bm*2+0] = sdx; ws[WS_DXY + bm*2+1] = sdy; }
    int o = t;
    float acc = sdx*(W1[5*O1+o] - W1[7*O1+o]) + sdy*(W1[6*O1+o] - W1[8*O1+o]);
    #pragma unroll 8
    for (int c = 0; c < 64; ++c) acc += rf[c]*W1[(74+c)*O1+o];
    ws[WS_V + bm*O1 + o] = acc;
  } else {
    // W2 fragment pack (no A1 dependence)
    unsigned short* wf = (unsigned short*)(ws + WS_W2F);
    for (int i = t; i < 8192; i += 128){
      int j = i & 7, ll = (i >> 3) & 63, ct = (i >> 9) & 3, k0q = i >> 11;
      int oo = k0q*32 + (ll >> 4)*8 + j, c = ct*16 + (ll & 15);
      wf[i] = f2bf(W2[oo*O2 + c]);
    }
  }
}

// ---------------- K2: cos matrix + row-max (stored inverted), no atomics ----------------
__global__ __launch_bounds__(256) void k2(float* __restrict__ ws){
  int blk = blockIdx.x; int b = blk >> 9, n = blk & 511; int t = threadIdx.x;
  int bn = b*N_ + n;
  __shared__ __align__(16) float sn[64];
  __shared__ float dnt[64*65];   // +1 pad: conflict-free row reads
  __shared__ float part[4*64];
  if (t < 64) sn[t] = ws[WS_SRCN + bn*64 + t];
  float lmax = -3.4e38f;
  for (int chunk = 0; chunk < 8; ++chunk){
    __syncthreads();
    const float4* src = (const float4*)(ws + WS_DSTN + (size_t)(b*M_ + chunk*64)*64);
    #pragma unroll
    for (int i = 0; i < 4; ++i){
      float4 v = src[t + i*256];
      int base = (t + i*256)*4; int mm = base >> 6, c = base & 63;
      float* dp = &dnt[mm*65 + c];
      dp[0]=v.x; dp[1]=v.y; dp[2]=v.z; dp[3]=v.w;
    }
    __syncthreads();
    {
      int mm = t & 63, cg = t >> 6;
      const float* dr = &dnt[mm*65 + cg*16];
      const float* sr = &sn[cg*16];
      float p = 0.f;
      #pragma unroll
      for (int k = 0; k < 16; ++k) p += sr[k]*dr[k];
      part[cg*64 + mm] = p;
    }
    __syncthreads();
    if (t < 64){
      float d = part[t] + part[64+t] + part[128+t] + part[192+t];
      ws[WS_COS + bn*M_ + chunk*64 + t] = d;
      lmax = fmaxf(lmax, d);
    }
  }
  if (t < 64){
    lmax = fmaxf(lmax, __shfl_xor(lmax,32)); lmax = fmaxf(lmax, __shfl_xor(lmax,16));
    lmax = fmaxf(lmax, __shfl_xor(lmax,8));  lmax = fmaxf(lmax, __shfl_xor(lmax,4));
    lmax = fmaxf(lmax, __shfl_xor(lmax,2));  lmax = fmaxf(lmax, __shfl_xor(lmax,1));
    if (t == 0) ws[WS_RMAX + bn] = 1.0f / (lmax + 1e-6f);
  }
}

// ---------------- K2r: per-column max (inverted) + col sums CEN/CS1/CS2 ----------------
__global__ __launch_bounds__(256) void k2r(const float* __restrict__ wxyz, float* __restrict__ ws){
  int blk = blockIdx.x;            // 64 blocks: b = blk>>5, 16-col group = blk&31
  int b = blk >> 5; int c0 = (blk & 31)*16;
  int t = threadIdx.x;
  int cl = t & 15, seg = t >> 4;   // 16 segs x 32 rows
  int col = c0 + cl;
  int bm = b*M_ + col;
  float dx = ws[WS_DXY + bm*2+0], dy = ws[WS_DXY + bm*2+1];
  float mx = -3.4e38f, se = 0.f, sc = 0.f, s1c = 0.f;
  for (int i = 0; i < 32; ++i){
    int bn = b*N_ + seg*32 + i;
    float cv = ws[WS_COS + (size_t)bn*M_ + col];
    float ri = ws[WS_RMAX + bn];
    float sx = wxyz[bn*3+0], sy = wxyz[bn*3+1];
    float ex = sx-dx, ey = sy-dy;
    se += sqrtf(ex*ex + ey*ey);
    mx = fmaxf(mx, cv);
    sc += cv;
    s1c += cv*ri;
  }
  __shared__ float r0[256], r1[256], r2[256], r3[256];
  r0[t]=mx; r1[t]=se; r2[t]=s1c; r3[t]=sc;
  __syncthreads();
  for (int s = 8; s > 0; s >>= 1){
    if (seg < s){
      int o2 = t + s*16;
      r0[t] = fmaxf(r0[t], r0[o2]); r1[t] += r1[o2]; r2[t] += r2[o2]; r3[t] += r3[o2];
    }
    __syncthreads();
  }
  if (t < 16){
    int bmw = b*M_ + c0 + t;
    float ci = 1.0f/(r0[t] + 1e-10f);
    ws[WS_CMAX + bmw] = ci;
    ws[WS_COLS + bmw] = r1[t];             // CEN
    ws[WS_COLS + 1024 + bmw] = r2[t];      // CS1
    ws[WS_COLS + 2048 + bmw] = r3[t]*ci;   // CS2
  }
}

// ---------------- K3a: row sums + 9 global scalar moments from COS pass ----------------
__global__ __launch_bounds__(256) void k3a(const float* __restrict__ wxyz, float* __restrict__ ws){
  int bn = blockIdx.x; int b = bn >> 9; int t = threadIdx.x;
  float ri = ws[WS_RMAX + bn];
  float sx = wxyz[bn*3+0], sy = wxyz[bn*3+1];
  float q[9];
  #pragma unroll
  for (int j = 0; j < 9; ++j) q[j] = 0.f;
  #pragma unroll
  for (int k = 0; k < 2; ++k){
    int m = t + k*256;
    float2 d = *(const float2*)(ws + WS_DXY + (size_t)(b*M_+m)*2);
    float ex = sx-d.x, ey = sy-d.y;
    float en = sqrtf(ex*ex + ey*ey);
    float cv = ws[WS_COS + (size_t)bn*M_ + m];
    float ci = ws[WS_CMAX + b*M_ + m];
    float s2 = cv*ci;
    q[0]+=en; q[1]+=cv; q[2]+=s2; q[3]+=en*en; q[4]+=cv*cv; q[5]+=s2*s2;
    q[6]+=en*cv; q[7]+=en*s2; q[8]+=cv*cv*ci;
  }
  #pragma unroll
  for (int j = 0; j < 9; ++j){
    float v = q[j];
    v += __shfl_xor(v,1); v += __shfl_xor(v,2); v += __shfl_xor(v,4);
    v += __shfl_xor(v,8); v += __shfl_xor(v,16); v += __shfl_xor(v,32);
    q[j] = v;
  }
  __shared__ float wr[9][4];
  int w = t >> 6;
  if ((t & 63) == 0){
    #pragma unroll
    for (int j = 0; j < 9; ++j) wr[j][w] = q[j];
  }
  __syncthreads();
  if (t < 9){
    float Q = wr[t][0] + wr[t][1] + wr[t][2] + wr[t][3];
    float f = (t==1 || t==6 || t==8) ? ri : ((t==4) ? ri*ri : 1.0f);
    float s = f*Q;
    if (t < 3) ws[WS_ROWS + t*1024 + bn] = s;   // REN, RS1(=ri*rcos), RS2
    atomicAdd(&ws[WS_SC2P + (bn & 63)*16 + t], s);
  }
}

// ---------------- K3s: closed-form BN1 per o -> A1/C1; write P0, W9S, Vf ----------------
__global__ __launch_bounds__(256) void k3s(const float* __restrict__ W1,
    const float* __restrict__ b1, const float* __restrict__ g1,
    const float* __restrict__ be1, float* __restrict__ ws){
  int o = blockIdx.x; int t = threadIdx.x;
  __shared__ float scal[9];
  __shared__ float wr[12][4];
  __shared__ float sA1, sC1;
  if (t < 9){
    float s = 0.f;
    #pragma unroll 8
    for (int r = 0; r < 64; ++r) s += ws[WS_SC2P + r*16 + t];
    scal[t] = s;
  }
  float b1o = b1[o];
  float uu[4], vv[4];
  float a[12];
  #pragma unroll
  for (int j = 0; j < 12; ++j) a[j] = 0.f;
  #pragma unroll
  for (int k = 0; k < 4; ++k){
    int i = t + k*256;
    float u = ws[WS_U + (size_t)i*O1 + o] + b1o;
    float v = ws[WS_V + (size_t)i*O1 + o];
    uu[k] = u; vv[k] = v;
    float ren = ws[WS_ROWS + i], rs1 = ws[WS_ROWS + 1024 + i], rs2 = ws[WS_ROWS + 2048 + i];
    float cen = ws[WS_COLS + i], cs1 = ws[WS_COLS + 1024 + i], cs2 = ws[WS_COLS + 2048 + i];
    a[0]+=u; a[1]+=u*u; a[2]+=u*ren; a[3]+=u*rs1; a[4]+=u*rs2;
    a[5]+=v; a[6]+=v*v; a[7]+=v*cen; a[8]+=v*cs1; a[9]+=v*cs2;
    if (k < 2){ a[10]+=u; a[11]+=v; }   // b=0 partial sums
  }
  #pragma unroll
  for (int j = 0; j < 12; ++j){
    float v = a[j];
    v += __shfl_xor(v,1); v += __shfl_xor(v,2); v += __shfl_xor(v,4);
    v += __shfl_xor(v,8); v += __shfl_xor(v,16); v += __shfl_xor(v,32);
    a[j] = v;
  }
  int w = t >> 6;
  if ((t & 63) == 0){
    #pragma unroll
    for (int j = 0; j < 12; ++j) wr[j][w] = a[j];
  }
  __syncthreads();
  if (t == 0){
    float A[12];
    #pragma unroll
    for (int j = 0; j < 12; ++j) A[j] = wr[j][0] + wr[j][1] + wr[j][2] + wr[j][3];
    float w9 = W1[9*O1+o], wa = W1[138*O1+o], wb = W1[139*O1+o];
    float S1 = 512.f*(A[0] + A[5]) + w9*scal[0] + wa*scal[1] + wb*scal[2];
    float Q1 = 512.f*(A[1] + A[6])
      + 2.f*(A[10]*A[11] + (A[0]-A[10])*(A[5]-A[11]))
      + w9*w9*scal[3] + wa*wa*scal[4] + wb*wb*scal[5]
      + 2.f*(w9*wa*scal[6] + w9*wb*scal[7] + wa*wb*scal[8])
      + 2.f*(w9*A[2] + wa*A[3] + wb*A[4])
      + 2.f*(w9*A[7] + wa*A[8] + wb*A[9]);
    float mu = S1/PBIG, var = Q1/PBIG - mu*mu;
    float istd = rsqrtf(var + 1e-5f);
    float A1v = g1[o]*istd;
    sA1 = A1v; sC1 = be1[o] - mu*A1v;
    ws[WS_W9S + o]       = w9*A1v;
    ws[WS_W9S + 128 + o] = wa*A1v;
    ws[WS_W9S + 256 + o] = wb*A1v;
  }
  __syncthreads();
  float A1 = sA1, C1 = sC1;
  int k0q = o >> 5, quad = (o >> 3) & 3, j = o & 7;
  #pragma unroll
  for (int k = 0; k < 4; ++k){
    int i = t + k*256;
    ws[WS_P0 + (size_t)i*O1 + o] = uu[k]*A1 + C1;
    int b = i >> 9, m = i & 511;
    int mc = m >> 7, w2 = (m >> 5) & 3, mt = (m >> 4) & 1, l16 = m & 15;
    ws[WS_VF + (size_t)(((b*4 + mc)*4 + w2)*4096) + k0q*1024 + mt*512 + (quad*16 + l16)*8 + j]
      = vv[k]*A1;
  }
}

// ---------------- K4: fragment-packed V loads (coalesced); uint4 x2 store; no spill ----
// block=256, min 4 waves/EU: VGPR ~52, NO scratch spill. (256,8) forced VGPR=32
// and spilled: WRITE_SIZE 280MB, dur 125us. Keep 4.
__global__ __launch_bounds__(256, 4) void k4(const float* __restrict__ wxyz,
    float* __restrict__ ws){
  int blk = blockIdx.x; int bn = blk >> 2, mc = blk & 3;
  int b = bn >> 9; int t = threadIdx.x;
  __shared__ __align__(16) unsigned short wBf[8192];        // 16 KB fragment-packed W2
  __shared__ __align__(16) float p0s[128], w9s[128], was[128], wbs[128];
  __shared__ float ls[64], lq[64];
  {   // stage W2 fragments: lane-consecutive 16B (conflict-free)
    const s8v* g = (const s8v*)(ws + WS_W2F);
    s8v* l = (s8v*)wBf;
    #pragma unroll
    for (int c2 = 0; c2 < 4; ++c2) l[c2*256 + t] = g[c2*256 + t];
  }
  if (t < 64){ ls[t] = 0.f; lq[t] = 0.f; }
  if (t < 128){
    p0s[t] = ws[WS_P0 + bn*O1 + t];
    w9s[t] = ws[WS_W9S + t];
    was[t] = ws[WS_W9S + 128 + t];
    wbs[t] = ws[WS_W9S + 256 + t];
  }
  __syncthreads();
  // barrier-free from here until the final stat reduce
  int ll = t & 63, w = t >> 6, l16 = ll & 15, quad = ll >> 4;
  float sx = wxyz[bn*3+0], sy = wxyz[bn*3+1];
  float ri = ws[WS_RMAX + bn];
  uint4* xf4 = (uint4*)(ws + WS_X2) + (size_t)bn*4096;
  union U8 { s8v v; unsigned u[4]; };
  int mA = mc*128 + w*32 + l16, mB = mA + 16;
  float2 dA = *(const float2*)(ws + WS_DXY + (size_t)(b*M_+mA)*2);
  float2 dB = *(const float2*)(ws + WS_DXY + (size_t)(b*M_+mB)*2);
  float cvA = ws[WS_COS + (size_t)bn*M_ + mA], cvB = ws[WS_COS + (size_t)bn*M_ + mB];
  float ciA = ws[WS_CMAX + b*M_ + mA],         ciB = ws[WS_CMAX + b*M_ + mB];
  float exA = sx-dA.x, eyA = sy-dA.y; float en0 = sqrtf(exA*exA + eyA*eyA);
  float exB = sx-dB.x, eyB = sy-dB.y; float en1 = sqrtf(exB*exB + eyB*eyB);
  float s10 = cvA*ri, s20 = cvA*ciA;
  float s11 = cvB*ri, s21 = cvB*ciB;
  const float* vfb = ws + WS_VF + (size_t)(((b*4 + mc)*4 + w)*4096) + ll*8;
  f4v acc[2][4];
  #pragma unroll
  for (int i = 0; i < 2; ++i)
    #pragma unroll
    for (int j = 0; j < 4; ++j) acc[i][j] = (f4v){0.f,0.f,0.f,0.f};
  #pragma unroll
  for (int k0q = 0; k0q < 4; ++k0q){
    int ko = k0q*32 + quad*8;
    f4v p0a = *(const f4v*)&p0s[ko], p0b = *(const f4v*)&p0s[ko+4];
    f4v w9a = *(const f4v*)&w9s[ko], w9b = *(const f4v*)&w9s[ko+4];
    f4v waa = *(const f4v*)&was[ko], wab = *(const f4v*)&was[ko+4];
    f4v wba = *(const f4v*)&wbs[ko], wbb = *(const f4v*)&wbs[ko+4];
    const float* vA = vfb + k0q*1024;
    const float* vB = vA + 512;
    f4v vA0 = *(const f4v*)(vA), vA1 = *(const f4v*)(vA + 4);
    f4v vB0 = *(const f4v*)(vB), vB1 = *(const f4v*)(vB + 4);
    f4v zaA = relu4(p0a + vA0 + en0*w9a + s10*waa + s20*wba);
    f4v zbA = relu4(p0b + vA1 + en0*w9b + s10*wab + s20*wbb);
    f4v zaB = relu4(p0a + vB0 + en1*w9a + s11*waa + s21*wba);
    f4v zbB = relu4(p0b + vB1 + en1*w9b + s11*wab + s21*wbb);
    U8 uA, uB;
    uA.u[0] = pk_trunc(zaA[0], zaA[1]); uA.u[1] = pk_trunc(zaA[2], zaA[3]);
    uA.u[2] = pk_trunc(zbA[0], zbA[1]); uA.u[3] = pk_trunc(zbA[2], zbA[3]);
    uB.u[0] = pk_trunc(zaB[0], zaB[1]); uB.u[1] = pk_trunc(zaB[2], zaB[3]);
    uB.u[2] = pk_trunc(zbB[0], zbB[1]); uB.u[3] = pk_trunc(zbB[2], zbB[3]);
    #pragma unroll
    for (int ct = 0; ct < 4; ++ct){
      s8v bb = *(const s8v*)&wBf[((k0q*4 + ct)*64 + ll)*8];
      acc[0][ct] = __builtin_amdgcn_mfma_f32_16x16x32_bf16(bb, uA.v, acc[0][ct], 0,0,0);
      acc[1][ct] = __builtin_amdgcn_mfma_f32_16x16x32_bf16(bb, uB.v, acc[1][ct], 0,0,0);
    }
  }
  // fragment-major store, 16 B/lane: wave writes 1024 B contiguous per inst
  #pragma unroll
  for (int mt = 0; mt < 2; ++mt){
    uint4 u0, u1;
    u0.x = pk2(acc[mt][0][0], acc[mt][0][1]); u0.y = pk2(acc[mt][0][2], acc[mt][0][3]);
    u0.z = pk2(acc[mt][1][0], acc[mt][1][1]); u0.w = pk2(acc[mt][1][2], acc[mt][1][3]);
    u1.x = pk2(acc[mt][2][0], acc[mt][2][1]); u1.y = pk2(acc[mt][2][2], acc[mt][2][3]);
    u1.z = pk2(acc[mt][3][0], acc[mt][3][1]); u1.w = pk2(acc[mt][3][2], acc[mt][3][3]);
    xf4[((((mc*4 + w)*2 + mt)*2 + 0)*64) + ll] = u0;
    xf4[((((mc*4 + w)*2 + mt)*2 + 1)*64) + ll] = u1;
  }
  // BN2 stat reduce: over the 16 lanes of each quad-group, then LDS
  #pragma unroll
  for (int ct = 0; ct < 4; ++ct){
    #pragma unroll
    for (int r = 0; r < 4; ++r){
      float a0 = acc[0][ct][r], a1 = acc[1][ct][r];
      float s = a0 + a1;
      float q = a0*a0 + a1*a1;
      s += __shfl_xor(s,1); s += __shfl_xor(s,2); s += __shfl_xor(s,4); s += __shfl_xor(s,8);
      q += __shfl_xor(q,1); q += __shfl_xor(q,2); q += __shfl_xor(q,4); q += __shfl_xor(q,8);
      if (l16 == 0){
        atomicAdd(&ls[ct*16 + quad*4 + r], s);
        atomicAdd(&lq[ct*16 + quad*4 + r], q);
      }
    }
  }
  __syncthreads();
  int rep = blk & 63;
  if (t < 64) atomicAdd(&ws[WS_ST2 + rep*128 + t], ls[t]);
  else if (t < 128) atomicAdd(&ws[WS_ST2 + rep*128 + t], lq[t-64]);
}

// ---------------- K5: BN2 + softmax pool from uint4 fragment-major x2 ----------------
__global__ __launch_bounds__(256) void k5(const float* __restrict__ g2,
    const float* __restrict__ be2, const float* __restrict__ M1w,
    const float* __restrict__ M1b, float* __restrict__ ws){
  int bn = blockIdx.x; int t = threadIdx.x;
  __shared__ float sa2[64], sc2[64];
  __shared__ float s_mx[512];
  __shared__ float s_aw[512];
  __shared__ float red[256];
  __shared__ float part[64*65];
  __shared__ float s_att[64];
  __shared__ float sgmax, sinvS;
  if (t < 64){
    float s = 0.f, q = 0.f;
    #pragma unroll 8
    for (int r = 0; r < 64; ++r){ s += ws[WS_ST2 + r*128 + t]; q += ws[WS_ST2 + r*128 + 64 + t]; }
    float mu = s/PBIG, var = q/PBIG - mu*mu;
    float istd = rsqrtf(var + 1e-5f);
    float A2 = g2[t]*istd;
    sa2[t] = A2; sc2[t] = be2[t] - mu*A2;
  }
  __syncthreads();
  int ll = t & 63, w = t >> 6, l16 = ll & 15, quad = ll >> 4;
  const uint4* xf4 = (const uint4*)(ws + WS_X2) + (size_t)bn*4096;
  uint4 xv[4][2][2];   // [mc][mt][cp]
  #pragma unroll
  for (int mc = 0; mc < 4; ++mc)
    #pragma unroll
    for (int mt = 0; mt < 2; ++mt)
      #pragma unroll
      for (int cp = 0; cp < 2; ++cp)
        xv[mc][mt][cp] = xf4[((((mc*4 + w)*2 + mt)*2 + cp)*64) + ll];
  float a2r[4][4], c2r[4][4];
  #pragma unroll
  for (int ct = 0; ct < 4; ++ct)
    #pragma unroll
    for (int r = 0; r < 4; ++r){
      int c = ct*16 + quad*4 + r;
      a2r[ct][r] = sa2[c]; c2r[ct][r] = sc2[c];
    }
  // Pass A: per-m max over channels; 2 shuffles (across quads)
  #pragma unroll
  for (int mc = 0; mc < 4; ++mc){
    #pragma unroll
    for (int mt = 0; mt < 2; ++mt){
      float mx = 0.f;   // relu >= 0
      #pragma unroll
      for (int cp = 0; cp < 2; ++cp){
        uint4 uv = xv[mc][mt][cp];
        int c0t = 2*cp, c1t = 2*cp + 1;
        float x0 = bf2f((unsigned short)(uv.x & 0xffffu));
        float x1 = bf2f((unsigned short)(uv.x >> 16));
        float x2 = bf2f((unsigned short)(uv.y & 0xffffu));
        float x3 = bf2f((unsigned short)(uv.y >> 16));
        float x4 = bf2f((unsigned short)(uv.z & 0xffffu));
        float x5 = bf2f((unsigned short)(uv.z >> 16));
        float x6 = bf2f((unsigned short)(uv.w & 0xffffu));
        float x7 = bf2f((unsigned short)(uv.w >> 16));
        mx = fmaxf(mx, a2r[c0t][0]*x0 + c2r[c0t][0]);
        mx = fmaxf(mx, a2r[c0t][1]*x1 + c2r[c0t][1]);
        mx = fmaxf(mx, a2r[c0t][2]*x2 + c2r[c0t][2]);
        mx = fmaxf(mx, a2r[c0t][3]*x3 + c2r[c0t][3]);
        mx = fmaxf(mx, a2r[c1t][0]*x4 + c2r[c1t][0]);
        mx = fmaxf(mx, a2r[c1t][1]*x5 + c2r[c1t][1]);
        mx = fmaxf(mx, a2r[c1t][2]*x6 + c2r[c1t][2]);
        mx = fmaxf(mx, a2r[c1t][3]*x7 + c2r[c1t][3]);
      }
      mx = fmaxf(mx, __shfl_xor(mx,16));
      mx = fmaxf(mx, __shfl_xor(mx,32));
      if (quad == 0) s_mx[mc*128 + w*32 + mt*16 + l16] = mx;
    }
  }
  __syncthreads();
  red[t] = fmaxf(s_mx[t], s_mx[t+256]);
  __syncthreads();
  for (int s = 128; s > 0; s >>= 1){ if (t < s) red[t] = fmaxf(red[t], red[t+s]); __syncthreads(); }
  if (t == 0) sgmax = red[0];
  __syncthreads();
  float e0 = expf(s_mx[t] - sgmax), e1 = expf(s_mx[t+256] - sgmax);
  s_aw[t] = e0; s_aw[t+256] = e1;
  red[t] = e0 + e1;
  __syncthreads();
  for (int s = 128; s > 0; s >>= 1){ if (t < s) red[t] += red[t+s]; __syncthreads(); }
  if (t == 0) sinvS = 1.0f / red[0];
  __syncthreads();
  // Pass C: weighted sum (y recomputed from registers)
  float acc[4][4];
  #pragma unroll
  for (int ct = 0; ct < 4; ++ct)
    #pragma unroll
    for (int r = 0; r < 4; ++r) acc[ct][r] = 0.f;
  #pragma unroll
  for (int mc = 0; mc < 4; ++mc){
    #pragma unroll
    for (int mt = 0; mt < 2; ++mt){
      float aw = s_aw[mc*128 + w*32 + mt*16 + l16];
      #pragma unroll
      for (int cp = 0; cp < 2; ++cp){
        uint4 uv = xv[mc][mt][cp];
        int c0t = 2*cp, c1t = 2*cp + 1;
        float x0 = bf2f((unsigned short)(uv.x & 0xffffu));
        float x1 = bf2f((unsigned short)(uv.x >> 16));
        float x2 = bf2f((unsigned short)(uv.y & 0xffffu));
        float x3 = bf2f((unsigned short)(uv.y >> 16));
        float x4 = bf2f((unsigned short)(uv.z & 0xffffu));
        float x5 = bf2f((unsigned short)(uv.z >> 16));
        float x6 = bf2f((unsigned short)(uv.w & 0xffffu));
        float x7 = bf2f((unsigned short)(uv.w >> 16));
        acc[c0t][0] += aw*fmaxf(a2r[c0t][0]*x0 + c2r[c0t][0], 0.f);
        acc[c0t][1] += aw*fmaxf(a2r[c0t][1]*x1 + c2r[c0t][1], 0.f);
        acc[c0t][2] += aw*fmaxf(a2r[c0t][2]*x2 + c2r[c0t][2], 0.f);
        acc[c0t][3] += aw*fmaxf(a2r[c0t][3]*x3 + c2r[c0t][3], 0.f);
        acc[c1t][0] += aw*fmaxf(a2r[c1t][0]*x4 + c2r[c1t][0], 0.f);
        acc[c1t][1] += aw*fmaxf(a2r[c1t][1]*x5 + c2r[c1t][1], 0.f);
        acc[c1t][2] += aw*fmaxf(a2r[c1t][2]*x6 + c2r[c1t][2], 0.f);
        acc[c1t][3] += aw*fmaxf(a2r[c1t][3]*x7 + c2r[c1t][3], 0.f);
      }
    }
  }
  int row = w*16 + l16;
  #pragma unroll
  for (int ct = 0; ct < 4; ++ct)
    #pragma unroll
    for (int r = 0; r < 4; ++r)
      part[row*65 + ct*16 + quad*4 + r] = acc[ct][r];
  __syncthreads();
  if (t < 64){
    float a = 0.f;
    #pragma unroll 8
    for (int r = 0; r < 64; ++r) a += part[r*65 + t];
    s_att[t] = a * sinvS;
  }
  __syncthreads();
  if (t < 32){
    float z = M1b[t];
    #pragma unroll 8
    for (int c = 0; c < 64; ++c) z += s_att[c]*M1w[c*32 + t];
    ws[WS_Z + bn*32 + t] = z;
    int rep = bn & 63;
    atomicAdd(&ws[WS_ST3 + rep*64 + t], z);
    atomicAdd(&ws[WS_ST3 + rep*64 + 32 + t], z*z);
  }
}

// ---------------- K6: BN3 + head L2 -> logits ----------------
__global__ __launch_bounds__(256) void k6(const float* __restrict__ M1g,
    const float* __restrict__ M1be, const float* __restrict__ M2w,
    const float* __restrict__ M2b, const float* __restrict__ ws, float* __restrict__ out){
  int t = threadIdx.x; int s = blockIdx.x*256 + t;
  __shared__ float sa3[32], sc3[32];
  if (t < 32){
    float su = 0.f, q = 0.f;
    #pragma unroll 8
    for (int r = 0; r < 64; ++r){ su += ws[WS_ST3 + r*64 + t]; q += ws[WS_ST3 + r*64 + 32 + t]; }
    float mu = su/P3, var = q/P3 - mu*mu;
    float istd = rsqrtf(var + 1e-5f);
    float A3 = M1g[t]*istd;
    sa3[t] = A3; sc3[t] = M1be[t] - mu*A3;
  }
  __syncthreads();
  float a0 = M2b[0], a1 = M2b[1];
  #pragma unroll
  for (int j = 0; j < 32; ++j){
    float y = fmaxf(ws[WS_Z + s*32 + j]*sa3[j] + sc3[j], 0.f);
    a0 += y*M2w[j*2+0]; a1 += y*M2w[j*2+1];
  }
  out[s*2+0] = a0; out[s*2+1] = a1;
}

extern "C" void kernel_launch(void* const* d_in, const int* in_sizes, int n_in,
                              void* d_out, int out_size, void* d_ws, size_t ws_size,
                              hipStream_t stream){
  const float* wxyz = (const float*)d_in[0];
  const float* wpts = (const float*)d_in[1];
  const float* rf3  = (const float*)d_in[2];
  const float* rf3i = (const float*)d_in[3];
  const float* lz   = (const float*)d_in[4];
  const float* W1   = (const float*)d_in[5];
  const float* b1   = (const float*)d_in[6];
  const float* g1   = (const float*)d_in[7];
  const float* be1  = (const float*)d_in[8];
  const float* W2   = (const float*)d_in[9];
  const float* g2   = (const float*)d_in[11];
  const float* be2  = (const float*)d_in[12];
  const float* M1w  = (const float*)d_in[13];
  const float* M1b  = (const float*)d_in[14];
  const float* M1g  = (const float*)d_in[15];
  const float* M1be = (const float*)d_in[16];
  const float* M2w  = (const float*)d_in[17];
  const float* M2b  = (const float*)d_in[18];
  float* ws  = (float*)d_ws;
  float* out = (float*)d_out;
  // zero SC2P + ST2 + ST3 (contiguous 935936..949248 = 13312 floats)
  hipMemsetAsync(ws + WS_SC2P, 0, 13312*sizeof(float), stream);
  k1 <<<2049,128,0,stream>>>(wxyz, wpts, lz, rf3, rf3i, W1, W2, ws);
  k2 <<<1024,256,0,stream>>>(ws);
  k2r<<<64,256,0,stream>>>(wxyz, ws);
  k3a<<<1024,256,0,stream>>>(wxyz, ws);
  k3s<<<128,256,0,stream>>>(W1, b1, g1, be1, ws);
  k4 <<<4096,256,0,stream>>>(wxyz, ws);
  k5 <<<1024,256,0,stream>>>(g2, be2, M1w, M1b, ws);
  k6 <<<4,256,0,stream>>>(M1g, M1be, M2w, M2b, ws, out);
}